// Round 3
// baseline (154.593 us; speedup 1.0000x reference)
//
#include <hip/hip_runtime.h>
#include <stdint.h>
#include <math.h>

typedef unsigned short u16;
typedef _Float16 f16;
typedef __attribute__((ext_vector_type(4))) float f32x4;
typedef __attribute__((ext_vector_type(8))) f16 h8;
typedef __attribute__((ext_vector_type(4))) f16 h4;
typedef __attribute__((ext_vector_type(2))) f16 h2;
typedef __attribute__((ext_vector_type(2))) __fp16 fp16x2;
typedef __attribute__((ext_vector_type(4))) unsigned int u32x4;
typedef __attribute__((ext_vector_type(4))) unsigned short u16x4;
typedef __attribute__((ext_vector_type(8))) unsigned short u16x8;

typedef const __attribute__((address_space(1))) u16 gas_u16;
typedef __attribute__((address_space(3))) u16 las_u16;

#define MFMA32(a,b,c) __builtin_amdgcn_mfma_f32_16x16x32_f16((a),(b),(c),0,0,0)
#define MFMA16(a,b,c) __builtin_amdgcn_mfma_f32_16x16x16f16((a),(b),(c),0,0,0)

__device__ __forceinline__ float h2f(u16 h){ f16 x; __builtin_memcpy(&x,&h,2); return (float)x; }
__device__ __forceinline__ u16 f2h(float f){ f16 x = (f16)f; u16 u; __builtin_memcpy(&u,&x,2); return u; }

__device__ __forceinline__ float fast_exp2(float x){
#if __has_builtin(__builtin_amdgcn_exp2f)
  return __builtin_amdgcn_exp2f(x);
#else
  return exp2f(x);
#endif
}

// pack two f32 -> two f16 in one v_cvt_pkrtz; bit-cast to _Float16 vector type
__device__ __forceinline__ h2 pkrtz(float a, float b){
  fp16x2 t = __builtin_amdgcn_cvt_pkrtz(a, b);
  h2 r; __builtin_memcpy(&r, &t, 4);
  return r;
}

// ---------------- fused fp32 -> fp16 convert (x, w1, w2 in one launch) ----------------
#define NA4 1572864
#define NB4 442368
#define NC4 147456
__global__ __launch_bounds__(256) void cvt3_kernel(
    const float* __restrict__ a, u16* __restrict__ da,
    const float* __restrict__ b, u16* __restrict__ db,
    const float* __restrict__ c, u16* __restrict__ dc)
{
  int i = blockIdx.x*256 + threadIdx.x;
  const float* s; u16* d; int off;
  if (i < NA4)            { s = a; d = da; off = i; }
  else if (i < NA4+NB4)   { s = b; d = db; off = i - NA4; }
  else if (i < NA4+NB4+NC4){ s = c; d = dc; off = i - NA4 - NB4; }
  else return;
  f32x4 v = ((const f32x4*)s)[off];
  u16x4 o;
  o[0]=f2h(v[0]); o[1]=f2h(v[1]); o[2]=f2h(v[2]); o[3]=f2h(v[3]);
  ((u16x4*)d)[off] = o;
}

// ---------------- fp16 GEMM, C = A(M x 768) * B(N x 768)^T + bias ----------------
// 2-phase double-buffered staging: STAGE(next) is issued BEFORE the current tile's
// ds_read+MFMA, so the barrier's vmcnt(0) drain waits only (latency - compute).
// XCD-chunked block remap: each XCD owns an 8-wide x-chunk (A panels pinned in its
// L2) and walks y fastest (B panel reused gy times back-to-back).
// mode 0: fused q/k row-normalize (+ logit_scale*log2e on q) and scatter into
//         q/k/v head buffers (N,H,L,D) fp16.  mode 1: fp32 out (M x 768).
__global__ __launch_bounds__(256) void gemm_kernel(
    const u16* __restrict__ A, const u16* __restrict__ B, const float* __restrict__ bias,
    int mode, u16* __restrict__ qh, u16* __restrict__ kh, u16* __restrict__ vh,
    float* __restrict__ outp, const float* __restrict__ lsb)
{
  __shared__ u16 lA[2][128*32];
  __shared__ u16 lB[2][128*32];
  const int tid = threadIdx.x;
  const int lane = tid & 63;
  const int w = tid >> 6, wr = w >> 1, wc = w & 1;
  const int lo = lane & 15, hi = lane >> 4;

  // --- XCD-aware remap (requires gridDim.x % 8 == 0; holds for 64) ---
  const int gx = gridDim.x, gy = gridDim.y;
  const int lin = blockIdx.y*gx + blockIdx.x;
  const int xcd = lin & 7, j8 = lin >> 3;          // consecutive lin round-robin XCDs
  const int xw = gx >> 3;
  const int bx = xcd*xw + j8 / gy;                 // bijective: j8 in [0, gx*gy/8)
  const int by = j8 % gy;

  f32x4 zero = {0.f,0.f,0.f,0.f};
  f32x4 acc[4][4];
#pragma unroll
  for (int a=0;a<4;a++)
#pragma unroll
    for (int b=0;b<4;b++) acc[a][b] = zero;
  const u16* Ag = A + (size_t)bx*128*768;
  const u16* Bg = B + (size_t)by*128*768;
  const int sr = tid >> 2;
  const int sce = (tid & 3) * 8;

#define STAGE(buf, kt) do { \
    __builtin_amdgcn_global_load_lds((gas_u16*)(Ag + (size_t)sr*768 + (kt) + sce),      (las_u16*)(&lA[buf][tid*8]),        16, 0, 0); \
    __builtin_amdgcn_global_load_lds((gas_u16*)(Ag + (size_t)(sr+64)*768 + (kt) + sce), (las_u16*)(&lA[buf][2048 + tid*8]), 16, 0, 0); \
    __builtin_amdgcn_global_load_lds((gas_u16*)(Bg + (size_t)sr*768 + (kt) + sce),      (las_u16*)(&lB[buf][tid*8]),        16, 0, 0); \
    __builtin_amdgcn_global_load_lds((gas_u16*)(Bg + (size_t)(sr+64)*768 + (kt) + sce), (las_u16*)(&lB[buf][2048 + tid*8]), 16, 0, 0); \
  } while(0)

  STAGE(0, 0);
  __syncthreads();
  int cur = 0;
  for (int kt = 0; kt < 768; kt += 32) {
    if (kt + 32 < 768) STAGE(cur^1, kt + 32);   // prefetch next tile into other buffer
    h8 af[4], bfr[4];
#pragma unroll
    for (int mf=0; mf<4; mf++) af[mf]  = *(const h8*)(&lA[cur][(wr*64 + mf*16 + lo)*32 + hi*8]);
#pragma unroll
    for (int nf=0; nf<4; nf++) bfr[nf] = *(const h8*)(&lB[cur][(wc*64 + nf*16 + lo)*32 + hi*8]);
#pragma unroll
    for (int mf=0; mf<4; mf++)
#pragma unroll
      for (int nf=0; nf<4; nf++)
        acc[mf][nf] = MFMA32(af[mf], bfr[nf], acc[mf][nf]);
    __syncthreads();   // drains vmcnt(0): prefetch landed; all reads of cur done
    cur ^= 1;
  }
#undef STAGE

  const int r0 = bx*128 + wr*64;
  const int j0 = by*128 + wc*64;
  if (mode == 0) {
    // j0 is 64-aligned and 768 % 64 == 0 -> this wc-block maps to exactly one
    // projection p and one head hh (wave-uniform).
    const int p = (j0 >= 1536) ? 2 : ((j0 >= 768) ? 1 : 0);
    const int c0 = j0 - p*768;
    const int hh = c0 >> 6;
    u16* dst = (p==0) ? qh : ((p==1) ? kh : vh);
    float bi[4];
#pragma unroll
    for (int nf=0;nf<4;nf++) bi[nf] = bias[j0 + nf*16 + lo];
    float qsc = 1.0f;
    if (p == 0) qsc = __expf(fminf(lsb[hh], 4.6051701859880913680f)) * 1.4426950408889634f;
    const bool dnorm = (p != 2);
#pragma unroll
    for (int mf=0; mf<4; mf++)
#pragma unroll
      for (int i=0;i<4;i++) {
        int r = r0 + mf*16 + 4*hi + i;
        int n = r & 7, l = r >> 3;
        float v[4]; float ss = 0.f;
#pragma unroll
        for (int nf=0;nf<4;nf++){ v[nf] = acc[mf][nf][i] + bi[nf]; ss += v[nf]*v[nf]; }
        float sc = 1.0f;
        if (dnorm) {
          // quarter-wave (16 lanes, lo=0..15) holds the full 64-wide d row
          ss += __shfl_xor(ss, 1);
          ss += __shfl_xor(ss, 2);
          ss += __shfl_xor(ss, 4);
          ss += __shfl_xor(ss, 8);
          sc = qsc / fmaxf(sqrtf(ss), 1e-12f);
        }
        size_t base = (((size_t)n*12 + hh)*1024 + l)*64;
#pragma unroll
        for (int nf=0;nf<4;nf++)
          dst[base + nf*16 + lo] = f2h(v[nf]*sc);
      }
  } else {
#pragma unroll
    for (int nf=0; nf<4; nf++) {
      int j = j0 + nf*16 + lo;
      float bi = bias[j];
#pragma unroll
      for (int mf=0; mf<4; mf++)
#pragma unroll
        for (int i=0;i<4;i++) {
          int r = r0 + mf*16 + 4*hi + i;
          outp[(size_t)r*768 + j] = acc[mf][nf][i] + bi;
        }
    }
  }
}

// ---------------- V transpose: (N,H,L,D) -> (N,H,D,L) ----------------
__global__ __launch_bounds__(256) void transpose_kernel(const u16* __restrict__ vh, u16* __restrict__ vt){
  __shared__ u16 tile[64*72];   // [l(64)][d] padded stride 72
  const int nh = blockIdx.y, lt = blockIdx.x, tid = threadIdx.x;
  const int r = tid >> 2, c0 = (tid & 3) * 16;
  const u16* src = vh + (size_t)nh*65536 + (size_t)(lt*64 + r)*64 + c0;
  u32x4 a = *(const u32x4*)src, b = *(const u32x4*)(src + 8);
  *(u32x4*)(tile + r*72 + c0)     = a;
  *(u32x4*)(tile + r*72 + c0 + 8) = b;
  __syncthreads();
  u16x8 o0, o1;
#pragma unroll
  for (int s=0;s<8;s++){ o0[s] = tile[(c0+s)*72 + r]; o1[s] = tile[(c0+8+s)*72 + r]; }
  u16* dst = vt + (size_t)nh*65536 + (size_t)r*1024 + lt*64 + c0;
  *(u16x8*)dst       = o0;
  *(u16x8*)(dst + 8) = o1;
}

// ---------------- flash attention (cosine-bounded: no running max needed) ----------------
// grid (8 q-tiles, 96 n*h), remapped so all 8 q-tiles of one (n,h) share an XCD.
// block 256 = 4 waves, each wave owns 32 q rows (two 16-row groups a/b).
// swapped QK^T: sT = mfma(Ktile, Q) -> lane holds S^T[k=kf*16+4hi+i][q=lo] in log2 units.
// Scores bounded by +-exp(min(ls,4.6))*log2e (= 14.43 here) so p = exp2(s) fits fp16
// normals with NO max subtraction / rescale. Row sums computed on the matrix pipe
// via an all-ones A-operand mfma16 (every lane ends up holding the full row sum).
// PV: C/D layout of QK^T == B-operand layout of mfma_f32_16x16x16f16, so the packed
// P fragment feeds PV directly from registers - no LDS repack.
__global__ __launch_bounds__(256) void flash_kernel(
    const u16* __restrict__ qh, const u16* __restrict__ kh, const u16* __restrict__ vt,
    u16* __restrict__ obuf, const float* __restrict__ hsv, const float* __restrict__ lsp)
{
  __shared__ u16 lK[2*64*72];    // double-buffered [k(64)][d(64)] pad 72
  __shared__ u16 lVT[2*64*72];   // double-buffered [d(64)][k(64)] pad 72
  // XCD-locality remap: linear id -> (xcd, idx); 12 heads x 8 q-tiles per XCD (3MB K+V in L2)
  const int lin = blockIdx.y*8 + blockIdx.x;
  const int xcd = lin & 7, g = lin >> 3;
  const int nh = xcd + 8*(g >> 3);
  const int qt = g & 7;
  const int h = nh % 12, n = nh / 12;
  const u16* Qp = qh + (size_t)nh*65536;
  const u16* Kp = kh + (size_t)nh*65536;
  const u16* Vp = vt + (size_t)nh*65536;
  const int tid = threadIdx.x, lane = tid & 63, w = tid >> 6;
  const int lo = lane & 15, hi = lane >> 4;

  // Q fragments for both q-groups: lane holds Q[q=lo(+16)][d = hi*8 + j]
  h8 qa0, qa1, qb0, qb1;
  {
    const u16* qrow = Qp + (size_t)(qt*128 + w*32 + lo)*64 + hi*8;
    qa0 = *(const h8*)qrow;          qa1 = *(const h8*)(qrow + 32);
    qb0 = *(const h8*)(qrow + 1024); qb1 = *(const h8*)(qrow + 1024 + 32);
  }
  const f32x4 zero = {0.f,0.f,0.f,0.f};
  f32x4 oA[4] = {zero,zero,zero,zero};   // O^T[d=db*16+4hi+i][q=lo]
  f32x4 oB[4] = {zero,zero,zero,zero};
  f32x4 lA4 = zero, lB4 = zero;          // row sums via ones-MFMA
  const h4 ones = {(f16)1.f,(f16)1.f,(f16)1.f,(f16)1.f};

  // fp16-overflow guard (0 for these inputs; uniform branch if ever nonzero)
  float OFF;
  {
    float b = __expf(fminf(lsp[h], 4.6051701859880913680f)) * 1.4426950408889634f;
    OFF = fmaxf(b - 15.5f, 0.f);
  }

  const int sr = tid >> 2;          // stage row (k for lK, d for lVT)
  const int sc = (tid & 3) * 16;    // stage col
  u32x4 ka, kb, va, vb;
  ka = *(const u32x4*)(Kp + (size_t)sr*64 + sc);
  kb = *(const u32x4*)(Kp + (size_t)sr*64 + sc + 8);
  va = *(const u32x4*)(Vp + (size_t)sr*1024 + sc);
  vb = *(const u32x4*)(Vp + (size_t)sr*1024 + sc + 8);
  *(u32x4*)(lK  + sr*72 + sc)     = ka;
  *(u32x4*)(lK  + sr*72 + sc + 8) = kb;
  *(u32x4*)(lVT + sr*72 + sc)     = va;
  *(u32x4*)(lVT + sr*72 + sc + 8) = vb;
  __syncthreads();

  for (int t = 0; t < 16; ++t) {
    const u16* cK = lK  + (t&1)*4608;
    const u16* cV = lVT + (t&1)*4608;
    u16* nK = lK  + ((t&1)^1)*4608;
    u16* nV = lVT + ((t&1)^1)*4608;
    if (t < 15) {  // issue next-tile loads early; HBM latency hides under compute
      ka = *(const u32x4*)(Kp + (size_t)(t+1)*4096 + (size_t)sr*64 + sc);
      kb = *(const u32x4*)(Kp + (size_t)(t+1)*4096 + (size_t)sr*64 + sc + 8);
      va = *(const u32x4*)(Vp + (size_t)sr*1024 + (t+1)*64 + sc);
      vb = *(const u32x4*)(Vp + (size_t)sr*1024 + (t+1)*64 + sc + 8);
    }
    // S^T = K . Q^T for both q-groups (K fragments shared -> LDS reads amortized 2x)
    f32x4 sa[4], sb[4];
#pragma unroll
    for (int kf=0; kf<4; kf++) {
      const u16* krow = cK + (kf*16 + lo)*72 + hi*8;
      h8 k0 = *(const h8*)krow;
      h8 k1 = *(const h8*)(krow + 32);
      sa[kf] = MFMA32(k1, qa1, MFMA32(k0, qa0, zero));
      sb[kf] = MFMA32(k1, qb1, MFMA32(k0, qb0, zero));
    }
    if (OFF != 0.f) {
#pragma unroll
      for (int kf=0;kf<4;kf++)
#pragma unroll
        for (int i=0;i<4;i++) { sa[kf][i] -= OFF; sb[kf][i] -= OFF; }
    }
    // p = exp2(s), packed straight into the mfma16 B-operand layout
    h4 pa[4], pb[4];
#pragma unroll
    for (int kf=0;kf<4;kf++) {
      h2 a01 = pkrtz(fast_exp2(sa[kf][0]), fast_exp2(sa[kf][1]));
      h2 a23 = pkrtz(fast_exp2(sa[kf][2]), fast_exp2(sa[kf][3]));
      pa[kf] = __builtin_shufflevector(a01, a23, 0, 1, 2, 3);
      h2 b01 = pkrtz(fast_exp2(sb[kf][0]), fast_exp2(sb[kf][1]));
      h2 b23 = pkrtz(fast_exp2(sb[kf][2]), fast_exp2(sb[kf][3]));
      pb[kf] = __builtin_shufflevector(b01, b23, 0, 1, 2, 3);
    }
    // row sums on the matrix pipe: every lane gets the full sum for its q=lo
#pragma unroll
    for (int kf=0;kf<4;kf++) {
      lA4 = MFMA16(ones, pa[kf], lA4);
      lB4 = MFMA16(ones, pb[kf], lB4);
    }
    // PV: O^T += VT-frag x P-frag, K=16 MFMAs, V fragments shared across q-groups
#pragma unroll
    for (int db=0; db<4; db++) {
#pragma unroll
      for (int kf=0; kf<4; kf++) {
        h4 vf = *(const h4*)(cV + (db*16 + lo)*72 + kf*16 + hi*4);
        oA[db] = MFMA16(vf, pa[kf], oA[db]);
        oB[db] = MFMA16(vf, pb[kf], oB[db]);
      }
    }
    if (t < 15) {  // write next tile into the other buffer; single barrier per iter
      *(u32x4*)(nK + sr*72 + sc)     = ka;
      *(u32x4*)(nK + sr*72 + sc + 8) = kb;
      *(u32x4*)(nV + sr*72 + sc)     = va;
      *(u32x4*)(nV + sr*72 + sc + 8) = vb;
    }
    __syncthreads();
  }
  // epilogue: O[q][d] = O^T / l * head_scale, store fp16 into (L,N,C)
  float hsc = hsv[h];
  float invA = hsc / lA4[0];
  float invB = hsc / lB4[0];
  int l0 = qt*128 + w*32 + lo;
  u16* dA = obuf + ((size_t)l0*8 + n)*768 + h*64;
  u16* dB = obuf + ((size_t)(l0+16)*8 + n)*768 + h*64;
#pragma unroll
  for (int db=0; db<4; db++) {
    u16x4 pk0, pk1;
#pragma unroll
    for (int i=0;i<4;i++) { pk0[i] = f2h(oA[db][i]*invA); pk1[i] = f2h(oB[db][i]*invB); }
    *(u16x4*)(dA + db*16 + hi*4) = pk0;
    *(u16x4*)(dB + db*16 + hi*4) = pk1;
  }
}

extern "C" void kernel_launch(void* const* d_in, const int* in_sizes, int n_in,
                              void* d_out, int out_size, void* d_ws, size_t ws_size,
                              hipStream_t stream)
{
  (void)in_sizes; (void)n_in; (void)out_size; (void)ws_size;
  const float* x  = (const float*)d_in[0];
  const float* w1 = (const float*)d_in[1];
  const float* b1 = (const float*)d_in[2];
  const float* ls = (const float*)d_in[3];
  const float* hs = (const float*)d_in[4];
  const float* w2 = (const float*)d_in[5];
  const float* b2 = (const float*)d_in[6];
  float* out = (float*)d_out;

  u16* x_bf  = (u16*)d_ws;            // 8192 x 768  (reused as ob after GEMM1)
  u16* w1_bf = x_bf  + 6291456;       // 2304 x 768
  u16* w2_bf = w1_bf + 1769472;       // 768 x 768
  u16* qh    = w2_bf + 589824;        // (N,H,L,D) normalized (+ls*log2e on q)
  u16* kh    = qh    + 6291456;
  u16* vh    = kh    + 6291456;
  u16* vt    = vh    + 6291456;       // (N,H,D,L)
  u16* ob    = x_bf;                  // (L,N,C) fp16, aliases x_bf

  cvt3_kernel<<<8448, 256, 0, stream>>>(x, x_bf, w1, w1_bf, w2, w2_bf);
  gemm_kernel<<<dim3(64,18), 256, 0, stream>>>(x_bf, w1_bf, b1, 0, qh, kh, vh, nullptr, ls);
  transpose_kernel<<<dim3(16,96), 256, 0, stream>>>(vh, vt);
  flash_kernel<<<dim3(8,96), 256, 0, stream>>>(qh, kh, vt, ob, hs, ls);
  gemm_kernel<<<dim3(64,6), 256, 0, stream>>>(ob, w2_bf, b2, 1, nullptr, nullptr, nullptr, out, ls);
}

// Round 4
// 154.315 us; speedup vs baseline: 1.0018x; 1.0018x over previous
//
#include <hip/hip_runtime.h>
#include <stdint.h>
#include <math.h>

typedef unsigned short u16;
typedef _Float16 f16;
typedef __attribute__((ext_vector_type(4))) float f32x4;
typedef __attribute__((ext_vector_type(8))) f16 h8;
typedef __attribute__((ext_vector_type(4))) f16 h4;
typedef __attribute__((ext_vector_type(2))) f16 h2;
typedef __attribute__((ext_vector_type(2))) __fp16 fp16x2;
typedef __attribute__((ext_vector_type(4))) unsigned int u32x4;
typedef __attribute__((ext_vector_type(4))) unsigned short u16x4;
typedef __attribute__((ext_vector_type(8))) unsigned short u16x8;

typedef const __attribute__((address_space(1))) u16 gas_u16;
typedef __attribute__((address_space(3))) u16 las_u16;

#define MFMA32(a,b,c) __builtin_amdgcn_mfma_f32_16x16x32_f16((a),(b),(c),0,0,0)
#define MFMA16(a,b,c) __builtin_amdgcn_mfma_f32_16x16x16f16((a),(b),(c),0,0,0)

__device__ __forceinline__ float h2f(u16 h){ f16 x; __builtin_memcpy(&x,&h,2); return (float)x; }
__device__ __forceinline__ u16 f2h(float f){ f16 x = (f16)f; u16 u; __builtin_memcpy(&u,&x,2); return u; }

__device__ __forceinline__ float fast_exp2(float x){
#if __has_builtin(__builtin_amdgcn_exp2f)
  return __builtin_amdgcn_exp2f(x);
#else
  return exp2f(x);
#endif
}

// pack two f32 -> two f16 in one v_cvt_pkrtz; bit-cast to _Float16 vector type
__device__ __forceinline__ h2 pkrtz(float a, float b){
  fp16x2 t = __builtin_amdgcn_cvt_pkrtz(a, b);
  h2 r; __builtin_memcpy(&r, &t, 4);
  return r;
}

// ---------------- fused fp32 -> fp16 convert (x, w1, w2 in one launch) ----------------
#define NA4 1572864
#define NB4 442368
#define NC4 147456
__global__ __launch_bounds__(256) void cvt3_kernel(
    const float* __restrict__ a, u16* __restrict__ da,
    const float* __restrict__ b, u16* __restrict__ db,
    const float* __restrict__ c, u16* __restrict__ dc)
{
  int i = blockIdx.x*256 + threadIdx.x;
  const float* s; u16* d; int off;
  if (i < NA4)            { s = a; d = da; off = i; }
  else if (i < NA4+NB4)   { s = b; d = db; off = i - NA4; }
  else if (i < NA4+NB4+NC4){ s = c; d = dc; off = i - NA4 - NB4; }
  else return;
  f32x4 v = ((const f32x4*)s)[off];
  u16x4 o;
  o[0]=f2h(v[0]); o[1]=f2h(v[1]); o[2]=f2h(v[2]); o[3]=f2h(v[3]);
  ((u16x4*)d)[off] = o;
}

// ---------------- fp16 GEMM, C = A(M x 768) * B(N x 768)^T + bias ----------------
// 2-phase double-buffered staging: STAGE(next) is issued BEFORE the current tile's
// ds_read+MFMA, so the barrier's vmcnt(0) drain waits only (latency - compute).
// Block mapping is the DEFAULT linear one: with gx=64 (0 mod 8), xcd = bx%8 is
// already pinned -> each XCD keeps its 8 A-panels L2-resident across all by-rows
// while one shared B-panel is hot. (Round-3 remap re-fetched A: +16MB, reverted.)
// mode 0: fused q/k row-normalize (+ logit_scale*log2e on q) and scatter into
//         q/k/v head buffers (N,H,L,D) fp16.  mode 1: fp32 out (M x 768).
__global__ __launch_bounds__(256) void gemm_kernel(
    const u16* __restrict__ A, const u16* __restrict__ B, const float* __restrict__ bias,
    int mode, u16* __restrict__ qh, u16* __restrict__ kh, u16* __restrict__ vh,
    float* __restrict__ outp, const float* __restrict__ lsb)
{
  __shared__ u16 lA[2][128*32];
  __shared__ u16 lB[2][128*32];
  const int tid = threadIdx.x;
  const int lane = tid & 63;
  const int w = tid >> 6, wr = w >> 1, wc = w & 1;
  const int lo = lane & 15, hi = lane >> 4;

  const int bx = blockIdx.x, by = blockIdx.y;

  f32x4 zero = {0.f,0.f,0.f,0.f};
  f32x4 acc[4][4];
#pragma unroll
  for (int a=0;a<4;a++)
#pragma unroll
    for (int b=0;b<4;b++) acc[a][b] = zero;
  const u16* Ag = A + (size_t)bx*128*768;
  const u16* Bg = B + (size_t)by*128*768;
  const int sr = tid >> 2;
  const int sce = (tid & 3) * 8;

#define STAGE(buf, kt) do { \
    __builtin_amdgcn_global_load_lds((gas_u16*)(Ag + (size_t)sr*768 + (kt) + sce),      (las_u16*)(&lA[buf][tid*8]),        16, 0, 0); \
    __builtin_amdgcn_global_load_lds((gas_u16*)(Ag + (size_t)(sr+64)*768 + (kt) + sce), (las_u16*)(&lA[buf][2048 + tid*8]), 16, 0, 0); \
    __builtin_amdgcn_global_load_lds((gas_u16*)(Bg + (size_t)sr*768 + (kt) + sce),      (las_u16*)(&lB[buf][tid*8]),        16, 0, 0); \
    __builtin_amdgcn_global_load_lds((gas_u16*)(Bg + (size_t)(sr+64)*768 + (kt) + sce), (las_u16*)(&lB[buf][2048 + tid*8]), 16, 0, 0); \
  } while(0)

  STAGE(0, 0);
  __syncthreads();
  int cur = 0;
  for (int kt = 0; kt < 768; kt += 32) {
    if (kt + 32 < 768) STAGE(cur^1, kt + 32);   // prefetch next tile into other buffer
    h8 af[4], bfr[4];
#pragma unroll
    for (int mf=0; mf<4; mf++) af[mf]  = *(const h8*)(&lA[cur][(wr*64 + mf*16 + lo)*32 + hi*8]);
#pragma unroll
    for (int nf=0; nf<4; nf++) bfr[nf] = *(const h8*)(&lB[cur][(wc*64 + nf*16 + lo)*32 + hi*8]);
#pragma unroll
    for (int mf=0; mf<4; mf++)
#pragma unroll
      for (int nf=0; nf<4; nf++)
        acc[mf][nf] = MFMA32(af[mf], bfr[nf], acc[mf][nf]);
    __syncthreads();   // drains vmcnt(0): prefetch landed; all reads of cur done
    cur ^= 1;
  }
#undef STAGE

  const int r0 = bx*128 + wr*64;
  const int j0 = by*128 + wc*64;
  if (mode == 0) {
    // j0 is 64-aligned and 768 % 64 == 0 -> this wc-block maps to exactly one
    // projection p and one head hh (wave-uniform).
    const int p = (j0 >= 1536) ? 2 : ((j0 >= 768) ? 1 : 0);
    const int c0 = j0 - p*768;
    const int hh = c0 >> 6;
    u16* dst = (p==0) ? qh : ((p==1) ? kh : vh);
    float bi[4];
#pragma unroll
    for (int nf=0;nf<4;nf++) bi[nf] = bias[j0 + nf*16 + lo];
    float qsc = 1.0f;
    if (p == 0) qsc = __expf(fminf(lsb[hh], 4.6051701859880913680f)) * 1.4426950408889634f;
    const bool dnorm = (p != 2);
#pragma unroll
    for (int mf=0; mf<4; mf++)
#pragma unroll
      for (int i=0;i<4;i++) {
        int r = r0 + mf*16 + 4*hi + i;
        int n = r & 7, l = r >> 3;
        float v[4]; float ss = 0.f;
#pragma unroll
        for (int nf=0;nf<4;nf++){ v[nf] = acc[mf][nf][i] + bi[nf]; ss += v[nf]*v[nf]; }
        float sc = 1.0f;
        if (dnorm) {
          // quarter-wave (16 lanes, lo=0..15) holds the full 64-wide d row
          ss += __shfl_xor(ss, 1);
          ss += __shfl_xor(ss, 2);
          ss += __shfl_xor(ss, 4);
          ss += __shfl_xor(ss, 8);
          sc = qsc / fmaxf(sqrtf(ss), 1e-12f);
        }
        size_t base = (((size_t)n*12 + hh)*1024 + l)*64;
#pragma unroll
        for (int nf=0;nf<4;nf++)
          dst[base + nf*16 + lo] = f2h(v[nf]*sc);
      }
  } else {
#pragma unroll
    for (int nf=0; nf<4; nf++) {
      int j = j0 + nf*16 + lo;
      float bi = bias[j];
#pragma unroll
      for (int mf=0; mf<4; mf++)
#pragma unroll
        for (int i=0;i<4;i++) {
          int r = r0 + mf*16 + 4*hi + i;
          outp[(size_t)r*768 + j] = acc[mf][nf][i] + bi;
        }
    }
  }
}

// ---------------- V transpose: (N,H,L,D) -> (N,H,D,L) ----------------
__global__ __launch_bounds__(256) void transpose_kernel(const u16* __restrict__ vh, u16* __restrict__ vt){
  __shared__ u16 tile[64*72];   // [l(64)][d] padded stride 72
  const int nh = blockIdx.y, lt = blockIdx.x, tid = threadIdx.x;
  const int r = tid >> 2, c0 = (tid & 3) * 16;
  const u16* src = vh + (size_t)nh*65536 + (size_t)(lt*64 + r)*64 + c0;
  u32x4 a = *(const u32x4*)src, b = *(const u32x4*)(src + 8);
  *(u32x4*)(tile + r*72 + c0)     = a;
  *(u32x4*)(tile + r*72 + c0 + 8) = b;
  __syncthreads();
  u16x8 o0, o1;
#pragma unroll
  for (int s=0;s<8;s++){ o0[s] = tile[(c0+s)*72 + r]; o1[s] = tile[(c0+8+s)*72 + r]; }
  u16* dst = vt + (size_t)nh*65536 + (size_t)r*1024 + lt*64 + c0;
  *(u16x8*)dst       = o0;
  *(u16x8*)(dst + 8) = o1;
}

// ---------------- flash attention (cosine-bounded: no running max needed) ----------------
// grid (8 q-tiles, 96 n*h), remapped so all 8 q-tiles of one (n,h) share an XCD.
// block 256 = 4 waves, each wave owns 32 q rows (two 16-row groups a/b).
// swapped QK^T: sT = mfma(Ktile, Q) -> lane holds S^T[k=kf*16+4hi+i][q=lo] in log2 units.
// Scores bounded by +-exp(min(ls,4.6))*log2e (= 14.43 here) so p = exp2(s) fits fp16
// normals with NO max subtraction / rescale. Row sums computed on the matrix pipe
// via an all-ones A-operand mfma16 (every lane ends up holding the full row sum).
// PV: C/D layout of QK^T == B-operand layout of mfma_f32_16x16x16f16, so the packed
// P fragment feeds PV directly from registers - no LDS repack.
__global__ __launch_bounds__(256) void flash_kernel(
    const u16* __restrict__ qh, const u16* __restrict__ kh, const u16* __restrict__ vt,
    u16* __restrict__ obuf, const float* __restrict__ hsv, const float* __restrict__ lsp)
{
  __shared__ u16 lK[2*64*72];    // double-buffered [k(64)][d(64)] pad 72
  __shared__ u16 lVT[2*64*72];   // double-buffered [d(64)][k(64)] pad 72
  // XCD-locality remap: linear id -> (xcd, idx); 12 heads x 8 q-tiles per XCD (3MB K+V in L2)
  const int lin = blockIdx.y*8 + blockIdx.x;
  const int xcd = lin & 7, g = lin >> 3;
  const int nh = xcd + 8*(g >> 3);
  const int qt = g & 7;
  const int h = nh % 12, n = nh / 12;
  const u16* Qp = qh + (size_t)nh*65536;
  const u16* Kp = kh + (size_t)nh*65536;
  const u16* Vp = vt + (size_t)nh*65536;
  const int tid = threadIdx.x, lane = tid & 63, w = tid >> 6;
  const int lo = lane & 15, hi = lane >> 4;

  // Q fragments for both q-groups: lane holds Q[q=lo(+16)][d = hi*8 + j]
  h8 qa0, qa1, qb0, qb1;
  {
    const u16* qrow = Qp + (size_t)(qt*128 + w*32 + lo)*64 + hi*8;
    qa0 = *(const h8*)qrow;          qa1 = *(const h8*)(qrow + 32);
    qb0 = *(const h8*)(qrow + 1024); qb1 = *(const h8*)(qrow + 1024 + 32);
  }
  const f32x4 zero = {0.f,0.f,0.f,0.f};
  f32x4 oA[4] = {zero,zero,zero,zero};   // O^T[d=db*16+4hi+i][q=lo]
  f32x4 oB[4] = {zero,zero,zero,zero};
  f32x4 lA4 = zero, lB4 = zero;          // row sums via ones-MFMA
  const h4 ones = {(f16)1.f,(f16)1.f,(f16)1.f,(f16)1.f};

  // fp16-overflow guard (0 for these inputs; uniform branch if ever nonzero)
  float OFF;
  {
    float b = __expf(fminf(lsp[h], 4.6051701859880913680f)) * 1.4426950408889634f;
    OFF = fmaxf(b - 15.5f, 0.f);
  }

  const int sr = tid >> 2;          // stage row (k for lK, d for lVT)
  const int sc = (tid & 3) * 16;    // stage col
  u32x4 ka, kb, va, vb;
  ka = *(const u32x4*)(Kp + (size_t)sr*64 + sc);
  kb = *(const u32x4*)(Kp + (size_t)sr*64 + sc + 8);
  va = *(const u32x4*)(Vp + (size_t)sr*1024 + sc);
  vb = *(const u32x4*)(Vp + (size_t)sr*1024 + sc + 8);
  *(u32x4*)(lK  + sr*72 + sc)     = ka;
  *(u32x4*)(lK  + sr*72 + sc + 8) = kb;
  *(u32x4*)(lVT + sr*72 + sc)     = va;
  *(u32x4*)(lVT + sr*72 + sc + 8) = vb;
  __syncthreads();

  for (int t = 0; t < 16; ++t) {
    const u16* cK = lK  + (t&1)*4608;
    const u16* cV = lVT + (t&1)*4608;
    u16* nK = lK  + ((t&1)^1)*4608;
    u16* nV = lVT + ((t&1)^1)*4608;
    if (t < 15) {  // issue next-tile loads early; HBM latency hides under compute
      ka = *(const u32x4*)(Kp + (size_t)(t+1)*4096 + (size_t)sr*64 + sc);
      kb = *(const u32x4*)(Kp + (size_t)(t+1)*4096 + (size_t)sr*64 + sc + 8);
      va = *(const u32x4*)(Vp + (size_t)sr*1024 + (t+1)*64 + sc);
      vb = *(const u32x4*)(Vp + (size_t)sr*1024 + (t+1)*64 + sc + 8);
    }
    // S^T = K . Q^T for both q-groups (K fragments shared -> LDS reads amortized 2x)
    f32x4 sa[4], sb[4];
#pragma unroll
    for (int kf=0; kf<4; kf++) {
      const u16* krow = cK + (kf*16 + lo)*72 + hi*8;
      h8 k0 = *(const h8*)krow;
      h8 k1 = *(const h8*)(krow + 32);
      sa[kf] = MFMA32(k1, qa1, MFMA32(k0, qa0, zero));
      sb[kf] = MFMA32(k1, qb1, MFMA32(k0, qb0, zero));
    }
    if (OFF != 0.f) {
#pragma unroll
      for (int kf=0;kf<4;kf++)
#pragma unroll
        for (int i=0;i<4;i++) { sa[kf][i] -= OFF; sb[kf][i] -= OFF; }
    }
    // p = exp2(s), packed straight into the mfma16 B-operand layout
    h4 pa[4], pb[4];
#pragma unroll
    for (int kf=0;kf<4;kf++) {
      h2 a01 = pkrtz(fast_exp2(sa[kf][0]), fast_exp2(sa[kf][1]));
      h2 a23 = pkrtz(fast_exp2(sa[kf][2]), fast_exp2(sa[kf][3]));
      pa[kf] = __builtin_shufflevector(a01, a23, 0, 1, 2, 3);
      h2 b01 = pkrtz(fast_exp2(sb[kf][0]), fast_exp2(sb[kf][1]));
      h2 b23 = pkrtz(fast_exp2(sb[kf][2]), fast_exp2(sb[kf][3]));
      pb[kf] = __builtin_shufflevector(b01, b23, 0, 1, 2, 3);
    }
    // row sums on the matrix pipe: every lane gets the full sum for its q=lo
#pragma unroll
    for (int kf=0;kf<4;kf++) {
      lA4 = MFMA16(ones, pa[kf], lA4);
      lB4 = MFMA16(ones, pb[kf], lB4);
    }
    // PV: O^T += VT-frag x P-frag, K=16 MFMAs, V fragments shared across q-groups
#pragma unroll
    for (int db=0; db<4; db++) {
#pragma unroll
      for (int kf=0; kf<4; kf++) {
        h4 vf = *(const h4*)(cV + (db*16 + lo)*72 + kf*16 + hi*4);
        oA[db] = MFMA16(vf, pa[kf], oA[db]);
        oB[db] = MFMA16(vf, pb[kf], oB[db]);
      }
    }
    if (t < 15) {  // write next tile into the other buffer; single barrier per iter
      *(u32x4*)(nK + sr*72 + sc)     = ka;
      *(u32x4*)(nK + sr*72 + sc + 8) = kb;
      *(u32x4*)(nV + sr*72 + sc)     = va;
      *(u32x4*)(nV + sr*72 + sc + 8) = vb;
    }
    __syncthreads();
  }
  // epilogue: O[q][d] = O^T / l * head_scale, store fp16 into (L,N,C)
  float hsc = hsv[h];
  float invA = hsc / lA4[0];
  float invB = hsc / lB4[0];
  int l0 = qt*128 + w*32 + lo;
  u16* dA = obuf + ((size_t)l0*8 + n)*768 + h*64;
  u16* dB = obuf + ((size_t)(l0+16)*8 + n)*768 + h*64;
#pragma unroll
  for (int db=0; db<4; db++) {
    u16x4 pk0, pk1;
#pragma unroll
    for (int i=0;i<4;i++) { pk0[i] = f2h(oA[db][i]*invA); pk1[i] = f2h(oB[db][i]*invB); }
    *(u16x4*)(dA + db*16 + hi*4) = pk0;
    *(u16x4*)(dB + db*16 + hi*4) = pk1;
  }
}

extern "C" void kernel_launch(void* const* d_in, const int* in_sizes, int n_in,
                              void* d_out, int out_size, void* d_ws, size_t ws_size,
                              hipStream_t stream)
{
  (void)in_sizes; (void)n_in; (void)out_size; (void)ws_size;
  const float* x  = (const float*)d_in[0];
  const float* w1 = (const float*)d_in[1];
  const float* b1 = (const float*)d_in[2];
  const float* ls = (const float*)d_in[3];
  const float* hs = (const float*)d_in[4];
  const float* w2 = (const float*)d_in[5];
  const float* b2 = (const float*)d_in[6];
  float* out = (float*)d_out;

  u16* x_bf  = (u16*)d_ws;            // 8192 x 768  (reused as ob after GEMM1)
  u16* w1_bf = x_bf  + 6291456;       // 2304 x 768
  u16* w2_bf = w1_bf + 1769472;       // 768 x 768
  u16* qh    = w2_bf + 589824;        // (N,H,L,D) normalized (+ls*log2e on q)
  u16* kh    = qh    + 6291456;
  u16* vh    = kh    + 6291456;
  u16* vt    = vh    + 6291456;       // (N,H,D,L)
  u16* ob    = x_bf;                  // (L,N,C) fp16, aliases x_bf

  cvt3_kernel<<<8448, 256, 0, stream>>>(x, x_bf, w1, w1_bf, w2, w2_bf);
  gemm_kernel<<<dim3(64,18), 256, 0, stream>>>(x_bf, w1_bf, b1, 0, qh, kh, vh, nullptr, ls);
  transpose_kernel<<<dim3(16,96), 256, 0, stream>>>(vh, vt);
  flash_kernel<<<dim3(8,96), 256, 0, stream>>>(qh, kh, vt, ob, hs, ls);
  gemm_kernel<<<dim3(64,6), 256, 0, stream>>>(ob, w2_bf, b2, 1, nullptr, nullptr, nullptr, out, ls);
}

// Round 5
// 145.400 us; speedup vs baseline: 1.0632x; 1.0613x over previous
//
#include <hip/hip_runtime.h>
#include <stdint.h>
#include <math.h>

typedef unsigned short u16;
typedef _Float16 f16;
typedef __attribute__((ext_vector_type(4))) float f32x4;
typedef __attribute__((ext_vector_type(8))) f16 h8;
typedef __attribute__((ext_vector_type(4))) f16 h4;
typedef __attribute__((ext_vector_type(2))) f16 h2;
typedef __attribute__((ext_vector_type(2))) __fp16 fp16x2;
typedef __attribute__((ext_vector_type(4))) unsigned int u32x4;
typedef __attribute__((ext_vector_type(4))) unsigned short u16x4;
typedef __attribute__((ext_vector_type(8))) unsigned short u16x8;

typedef const __attribute__((address_space(1))) u16 gas_u16;
typedef __attribute__((address_space(3))) u16 las_u16;

#define MFMA32(a,b,c) __builtin_amdgcn_mfma_f32_16x16x32_f16((a),(b),(c),0,0,0)
#define MFMA16(a,b,c) __builtin_amdgcn_mfma_f32_16x16x16f16((a),(b),(c),0,0,0)

__device__ __forceinline__ float h2f(u16 h){ f16 x; __builtin_memcpy(&x,&h,2); return (float)x; }
__device__ __forceinline__ u16 f2h(float f){ f16 x = (f16)f; u16 u; __builtin_memcpy(&u,&x,2); return u; }

__device__ __forceinline__ float fast_exp2(float x){
#if __has_builtin(__builtin_amdgcn_exp2f)
  return __builtin_amdgcn_exp2f(x);
#else
  return exp2f(x);
#endif
}

// pack two f32 -> two f16 in one v_cvt_pkrtz; bit-cast to _Float16 vector type
__device__ __forceinline__ h2 pkrtz(float a, float b){
  fp16x2 t = __builtin_amdgcn_cvt_pkrtz(a, b);
  h2 r; __builtin_memcpy(&r, &t, 4);
  return r;
}

// ---------------- fused fp32 -> fp16 convert (x, w1, w2 in one launch) ----------------
#define NA4 1572864
#define NB4 442368
#define NC4 147456
__global__ __launch_bounds__(256) void cvt3_kernel(
    const float* __restrict__ a, u16* __restrict__ da,
    const float* __restrict__ b, u16* __restrict__ db,
    const float* __restrict__ c, u16* __restrict__ dc)
{
  int i = blockIdx.x*256 + threadIdx.x;
  const float* s; u16* d; int off;
  if (i < NA4)            { s = a; d = da; off = i; }
  else if (i < NA4+NB4)   { s = b; d = db; off = i - NA4; }
  else if (i < NA4+NB4+NC4){ s = c; d = dc; off = i - NA4 - NB4; }
  else return;
  f32x4 v = ((const f32x4*)s)[off];
  u16x4 o;
  o[0]=f2h(v[0]); o[1]=f2h(v[1]); o[2]=f2h(v[2]); o[3]=f2h(v[3]);
  ((u16x4*)d)[off] = o;
}

// ---------------- fp16 GEMM, C = A(M x 768) * B(N x 768)^T + bias ----------------
// Single-buffer 2-barrier loop (round-2 structure, proven fastest: inter-block TLP
// at 5 blocks/CU already hides staging latency; intra-block dbuf regressed).
// LDS XOR swizzle (T2, both-sides): global_load_lds writes linearly, so the 16B
// slot is swizzled on the GLOBAL SOURCE side (slot = (tid&3) ^ (row&3)) and the
// same XOR is applied on the ds_read side (slot = hi ^ (row&3)). Spreads the
// stride-64B fragment reads from 2 start-banks to 8 -> kills the 3.5M conflicts.
// mode 0: fused q/k row-normalize (+ logit_scale*log2e on q) and scatter into
//         q/k/v head buffers (N,H,L,D) fp16.  mode 1: fp32 out (M x 768).
__global__ __launch_bounds__(256) void gemm_kernel(
    const u16* __restrict__ A, const u16* __restrict__ B, const float* __restrict__ bias,
    int mode, u16* __restrict__ qh, u16* __restrict__ kh, u16* __restrict__ vh,
    float* __restrict__ outp, const float* __restrict__ lsb)
{
  __shared__ u16 lA[128*32];
  __shared__ u16 lB[128*32];
  const int tid = threadIdx.x;
  const int lane = tid & 63;
  const int w = tid >> 6, wr = w >> 1, wc = w & 1;
  const int lo = lane & 15, hi = lane >> 4;

  const int bx = blockIdx.x, by = blockIdx.y;

  f32x4 zero = {0.f,0.f,0.f,0.f};
  f32x4 acc[4][4];
#pragma unroll
  for (int a=0;a<4;a++)
#pragma unroll
    for (int b=0;b<4;b++) acc[a][b] = zero;
  const u16* Ag = A + (size_t)bx*128*768;
  const u16* Bg = B + (size_t)by*128*768;
  const int sr = tid >> 2;                       // dest row (0..63), +64 for 2nd half
  const int sce = (((tid & 3) ^ (sr & 3)) * 8);  // pre-swizzled source 16B-slot

  for (int kt = 0; kt < 768; kt += 32) {
    __builtin_amdgcn_global_load_lds((gas_u16*)(Ag + (size_t)sr*768 + kt + sce),      (las_u16*)(lA + tid*8),        16, 0, 0);
    __builtin_amdgcn_global_load_lds((gas_u16*)(Ag + (size_t)(sr+64)*768 + kt + sce), (las_u16*)(lA + 2048 + tid*8), 16, 0, 0);
    __builtin_amdgcn_global_load_lds((gas_u16*)(Bg + (size_t)sr*768 + kt + sce),      (las_u16*)(lB + tid*8),        16, 0, 0);
    __builtin_amdgcn_global_load_lds((gas_u16*)(Bg + (size_t)(sr+64)*768 + kt + sce), (las_u16*)(lB + 2048 + tid*8), 16, 0, 0);
    __syncthreads();
    h8 af[4], bfr[4];
    const int sla = hi ^ (lo & 3);   // swizzled read slot (row%4 == lo%4 for frag rows)
#pragma unroll
    for (int mf=0; mf<4; mf++) af[mf]  = *(const h8*)(lA + (wr*64 + mf*16 + lo)*32 + sla*8);
#pragma unroll
    for (int nf=0; nf<4; nf++) bfr[nf] = *(const h8*)(lB + (wc*64 + nf*16 + lo)*32 + sla*8);
#pragma unroll
    for (int mf=0; mf<4; mf++)
#pragma unroll
      for (int nf=0; nf<4; nf++)
        acc[mf][nf] = MFMA32(af[mf], bfr[nf], acc[mf][nf]);
    __syncthreads();
  }

  const int r0 = bx*128 + wr*64;
  const int j0 = by*128 + wc*64;
  if (mode == 0) {
    // j0 is 64-aligned and 768 % 64 == 0 -> this wc-block maps to exactly one
    // projection p and one head hh (wave-uniform).
    const int p = (j0 >= 1536) ? 2 : ((j0 >= 768) ? 1 : 0);
    const int c0 = j0 - p*768;
    const int hh = c0 >> 6;
    u16* dst = (p==0) ? qh : ((p==1) ? kh : vh);
    float bi[4];
#pragma unroll
    for (int nf=0;nf<4;nf++) bi[nf] = bias[j0 + nf*16 + lo];
    float qsc = 1.0f;
    if (p == 0) qsc = __expf(fminf(lsb[hh], 4.6051701859880913680f)) * 1.4426950408889634f;
    const bool dnorm = (p != 2);
#pragma unroll
    for (int mf=0; mf<4; mf++)
#pragma unroll
      for (int i=0;i<4;i++) {
        int r = r0 + mf*16 + 4*hi + i;
        int n = r & 7, l = r >> 3;
        float v[4]; float ss = 0.f;
#pragma unroll
        for (int nf=0;nf<4;nf++){ v[nf] = acc[mf][nf][i] + bi[nf]; ss += v[nf]*v[nf]; }
        float sc = 1.0f;
        if (dnorm) {
          // quarter-wave (16 lanes, lo=0..15) holds the full 64-wide d row
          ss += __shfl_xor(ss, 1);
          ss += __shfl_xor(ss, 2);
          ss += __shfl_xor(ss, 4);
          ss += __shfl_xor(ss, 8);
          sc = qsc / fmaxf(sqrtf(ss), 1e-12f);
        }
        size_t base = (((size_t)n*12 + hh)*1024 + l)*64;
#pragma unroll
        for (int nf=0;nf<4;nf++)
          dst[base + nf*16 + lo] = f2h(v[nf]*sc);
      }
  } else {
#pragma unroll
    for (int nf=0; nf<4; nf++) {
      int j = j0 + nf*16 + lo;
      float bi = bias[j];
#pragma unroll
      for (int mf=0; mf<4; mf++)
#pragma unroll
        for (int i=0;i<4;i++) {
          int r = r0 + mf*16 + 4*hi + i;
          outp[(size_t)r*768 + j] = acc[mf][nf][i] + bi;
        }
    }
  }
}

// ---------------- V transpose: (N,H,L,D) -> (N,H,D,L) ----------------
__global__ __launch_bounds__(256) void transpose_kernel(const u16* __restrict__ vh, u16* __restrict__ vt){
  __shared__ u16 tile[64*72];   // [l(64)][d] padded stride 72
  const int nh = blockIdx.y, lt = blockIdx.x, tid = threadIdx.x;
  const int r = tid >> 2, c0 = (tid & 3) * 16;
  const u16* src = vh + (size_t)nh*65536 + (size_t)(lt*64 + r)*64 + c0;
  u32x4 a = *(const u32x4*)src, b = *(const u32x4*)(src + 8);
  *(u32x4*)(tile + r*72 + c0)     = a;
  *(u32x4*)(tile + r*72 + c0 + 8) = b;
  __syncthreads();
  u16x8 o0, o1;
#pragma unroll
  for (int s=0;s<8;s++){ o0[s] = tile[(c0+s)*72 + r]; o1[s] = tile[(c0+8+s)*72 + r]; }
  u16* dst = vt + (size_t)nh*65536 + (size_t)r*1024 + lt*64 + c0;
  *(u16x8*)dst       = o0;
  *(u16x8*)(dst + 8) = o1;
}

// ---------------- flash attention (cosine-bounded: no running max needed) ----------------
// grid (8 q-tiles, 96 n*h), remapped so all 8 q-tiles of one (n,h) share an XCD.
// block 256 = 4 waves, each wave owns 32 q rows (two 16-row groups a/b).
// swapped QK^T: sT = mfma(Ktile, Q) -> lane holds S^T[k=kf*16+4hi+i][q=lo] in log2 units.
// Scores bounded by +-exp(min(ls,4.6))*log2e (= 14.43 here) so p = exp2(s) fits fp16
// normals with NO max subtraction / rescale. Row sums computed on the matrix pipe
// via an all-ones A-operand mfma16 (every lane ends up holding the full row sum).
// PV: C/D layout of QK^T == B-operand layout of mfma_f32_16x16x16f16, so the packed
// P fragment feeds PV directly from registers - no LDS repack.
__global__ __launch_bounds__(256) void flash_kernel(
    const u16* __restrict__ qh, const u16* __restrict__ kh, const u16* __restrict__ vt,
    u16* __restrict__ obuf, const float* __restrict__ hsv, const float* __restrict__ lsp)
{
  __shared__ u16 lK[2*64*72];    // double-buffered [k(64)][d(64)] pad 72
  __shared__ u16 lVT[2*64*72];   // double-buffered [d(64)][k(64)] pad 72
  // XCD-locality remap: linear id -> (xcd, idx); 12 heads x 8 q-tiles per XCD (3MB K+V in L2)
  const int lin = blockIdx.y*8 + blockIdx.x;
  const int xcd = lin & 7, g = lin >> 3;
  const int nh = xcd + 8*(g >> 3);
  const int qt = g & 7;
  const int h = nh % 12, n = nh / 12;
  const u16* Qp = qh + (size_t)nh*65536;
  const u16* Kp = kh + (size_t)nh*65536;
  const u16* Vp = vt + (size_t)nh*65536;
  const int tid = threadIdx.x, lane = tid & 63, w = tid >> 6;
  const int lo = lane & 15, hi = lane >> 4;

  // Q fragments for both q-groups: lane holds Q[q=lo(+16)][d = hi*8 + j]
  h8 qa0, qa1, qb0, qb1;
  {
    const u16* qrow = Qp + (size_t)(qt*128 + w*32 + lo)*64 + hi*8;
    qa0 = *(const h8*)qrow;          qa1 = *(const h8*)(qrow + 32);
    qb0 = *(const h8*)(qrow + 1024); qb1 = *(const h8*)(qrow + 1024 + 32);
  }
  const f32x4 zero = {0.f,0.f,0.f,0.f};
  f32x4 oA[4] = {zero,zero,zero,zero};   // O^T[d=db*16+4hi+i][q=lo]
  f32x4 oB[4] = {zero,zero,zero,zero};
  f32x4 lA4 = zero, lB4 = zero;          // row sums via ones-MFMA
  const h4 ones = {(f16)1.f,(f16)1.f,(f16)1.f,(f16)1.f};

  // fp16-overflow guard (0 for these inputs; uniform branch if ever nonzero)
  float OFF;
  {
    float b = __expf(fminf(lsp[h], 4.6051701859880913680f)) * 1.4426950408889634f;
    OFF = fmaxf(b - 15.5f, 0.f);
  }

  const int sr = tid >> 2;          // stage row (k for lK, d for lVT)
  const int sc = (tid & 3) * 16;    // stage col
  u32x4 ka, kb, va, vb;
  ka = *(const u32x4*)(Kp + (size_t)sr*64 + sc);
  kb = *(const u32x4*)(Kp + (size_t)sr*64 + sc + 8);
  va = *(const u32x4*)(Vp + (size_t)sr*1024 + sc);
  vb = *(const u32x4*)(Vp + (size_t)sr*1024 + sc + 8);
  *(u32x4*)(lK  + sr*72 + sc)     = ka;
  *(u32x4*)(lK  + sr*72 + sc + 8) = kb;
  *(u32x4*)(lVT + sr*72 + sc)     = va;
  *(u32x4*)(lVT + sr*72 + sc + 8) = vb;
  __syncthreads();

  for (int t = 0; t < 16; ++t) {
    const u16* cK = lK  + (t&1)*4608;
    const u16* cV = lVT + (t&1)*4608;
    u16* nK = lK  + ((t&1)^1)*4608;
    u16* nV = lVT + ((t&1)^1)*4608;
    if (t < 15) {  // issue next-tile loads early; HBM latency hides under compute
      ka = *(const u32x4*)(Kp + (size_t)(t+1)*4096 + (size_t)sr*64 + sc);
      kb = *(const u32x4*)(Kp + (size_t)(t+1)*4096 + (size_t)sr*64 + sc + 8);
      va = *(const u32x4*)(Vp + (size_t)sr*1024 + (t+1)*64 + sc);
      vb = *(const u32x4*)(Vp + (size_t)sr*1024 + (t+1)*64 + sc + 8);
    }
    // S^T = K . Q^T for both q-groups (K fragments shared -> LDS reads amortized 2x)
    f32x4 sa[4], sb[4];
#pragma unroll
    for (int kf=0; kf<4; kf++) {
      const u16* krow = cK + (kf*16 + lo)*72 + hi*8;
      h8 k0 = *(const h8*)krow;
      h8 k1 = *(const h8*)(krow + 32);
      sa[kf] = MFMA32(k1, qa1, MFMA32(k0, qa0, zero));
      sb[kf] = MFMA32(k1, qb1, MFMA32(k0, qb0, zero));
    }
    if (OFF != 0.f) {
#pragma unroll
      for (int kf=0;kf<4;kf++)
#pragma unroll
        for (int i=0;i<4;i++) { sa[kf][i] -= OFF; sb[kf][i] -= OFF; }
    }
    // p = exp2(s), packed straight into the mfma16 B-operand layout
    h4 pa[4], pb[4];
#pragma unroll
    for (int kf=0;kf<4;kf++) {
      h2 a01 = pkrtz(fast_exp2(sa[kf][0]), fast_exp2(sa[kf][1]));
      h2 a23 = pkrtz(fast_exp2(sa[kf][2]), fast_exp2(sa[kf][3]));
      pa[kf] = __builtin_shufflevector(a01, a23, 0, 1, 2, 3);
      h2 b01 = pkrtz(fast_exp2(sb[kf][0]), fast_exp2(sb[kf][1]));
      h2 b23 = pkrtz(fast_exp2(sb[kf][2]), fast_exp2(sb[kf][3]));
      pb[kf] = __builtin_shufflevector(b01, b23, 0, 1, 2, 3);
    }
    // row sums on the matrix pipe: every lane gets the full sum for its q=lo
#pragma unroll
    for (int kf=0;kf<4;kf++) {
      lA4 = MFMA16(ones, pa[kf], lA4);
      lB4 = MFMA16(ones, pb[kf], lB4);
    }
    // PV: O^T += VT-frag x P-frag, K=16 MFMAs, V fragments shared across q-groups
#pragma unroll
    for (int db=0; db<4; db++) {
#pragma unroll
      for (int kf=0; kf<4; kf++) {
        h4 vf = *(const h4*)(cV + (db*16 + lo)*72 + kf*16 + hi*4);
        oA[db] = MFMA16(vf, pa[kf], oA[db]);
        oB[db] = MFMA16(vf, pb[kf], oB[db]);
      }
    }
    if (t < 15) {  // write next tile into the other buffer; single barrier per iter
      *(u32x4*)(nK + sr*72 + sc)     = ka;
      *(u32x4*)(nK + sr*72 + sc + 8) = kb;
      *(u32x4*)(nV + sr*72 + sc)     = va;
      *(u32x4*)(nV + sr*72 + sc + 8) = vb;
    }
    __syncthreads();
  }
  // epilogue: O[q][d] = O^T / l * head_scale, store fp16 into (L,N,C)
  float hsc = hsv[h];
  float invA = hsc / lA4[0];
  float invB = hsc / lB4[0];
  int l0 = qt*128 + w*32 + lo;
  u16* dA = obuf + ((size_t)l0*8 + n)*768 + h*64;
  u16* dB = obuf + ((size_t)(l0+16)*8 + n)*768 + h*64;
#pragma unroll
  for (int db=0; db<4; db++) {
    u16x4 pk0, pk1;
#pragma unroll
    for (int i=0;i<4;i++) { pk0[i] = f2h(oA[db][i]*invA); pk1[i] = f2h(oB[db][i]*invB); }
    *(u16x4*)(dA + db*16 + hi*4) = pk0;
    *(u16x4*)(dB + db*16 + hi*4) = pk1;
  }
}

extern "C" void kernel_launch(void* const* d_in, const int* in_sizes, int n_in,
                              void* d_out, int out_size, void* d_ws, size_t ws_size,
                              hipStream_t stream)
{
  (void)in_sizes; (void)n_in; (void)out_size; (void)ws_size;
  const float* x  = (const float*)d_in[0];
  const float* w1 = (const float*)d_in[1];
  const float* b1 = (const float*)d_in[2];
  const float* ls = (const float*)d_in[3];
  const float* hs = (const float*)d_in[4];
  const float* w2 = (const float*)d_in[5];
  const float* b2 = (const float*)d_in[6];
  float* out = (float*)d_out;

  u16* x_bf  = (u16*)d_ws;            // 8192 x 768  (reused as ob after GEMM1)
  u16* w1_bf = x_bf  + 6291456;       // 2304 x 768
  u16* w2_bf = w1_bf + 1769472;       // 768 x 768
  u16* qh    = w2_bf + 589824;        // (N,H,L,D) normalized (+ls*log2e on q)
  u16* kh    = qh    + 6291456;
  u16* vh    = kh    + 6291456;
  u16* vt    = vh    + 6291456;       // (N,H,D,L)
  u16* ob    = x_bf;                  // (L,N,C) fp16, aliases x_bf

  cvt3_kernel<<<8448, 256, 0, stream>>>(x, x_bf, w1, w1_bf, w2, w2_bf);
  gemm_kernel<<<dim3(64,18), 256, 0, stream>>>(x_bf, w1_bf, b1, 0, qh, kh, vh, nullptr, ls);
  transpose_kernel<<<dim3(16,96), 256, 0, stream>>>(vh, vt);
  flash_kernel<<<dim3(8,96), 256, 0, stream>>>(qh, kh, vt, ob, hs, ls);
  gemm_kernel<<<dim3(64,6), 256, 0, stream>>>(ob, w2_bf, b2, 1, nullptr, nullptr, nullptr, out, ls);
}

// Round 6
// 138.872 us; speedup vs baseline: 1.1132x; 1.0470x over previous
//
#include <hip/hip_runtime.h>
#include <stdint.h>
#include <math.h>

typedef unsigned short u16;
typedef _Float16 f16;
typedef __attribute__((ext_vector_type(4))) float f32x4;
typedef __attribute__((ext_vector_type(8))) f16 h8;
typedef __attribute__((ext_vector_type(4))) f16 h4;
typedef __attribute__((ext_vector_type(2))) f16 h2;
typedef __attribute__((ext_vector_type(2))) __fp16 fp16x2;
typedef __attribute__((ext_vector_type(4))) unsigned int u32x4;
typedef __attribute__((ext_vector_type(4))) unsigned short u16x4;
typedef __attribute__((ext_vector_type(8))) unsigned short u16x8;

typedef const __attribute__((address_space(1))) u16 gas_u16;
typedef __attribute__((address_space(3))) u16 las_u16;

#define MFMA32(a,b,c) __builtin_amdgcn_mfma_f32_16x16x32_f16((a),(b),(c),0,0,0)
#define MFMA16(a,b,c) __builtin_amdgcn_mfma_f32_16x16x16f16((a),(b),(c),0,0,0)

__device__ __forceinline__ float h2f(u16 h){ f16 x; __builtin_memcpy(&x,&h,2); return (float)x; }
__device__ __forceinline__ u16 f2h(float f){ f16 x = (f16)f; u16 u; __builtin_memcpy(&u,&x,2); return u; }

__device__ __forceinline__ float fast_exp2(float x){
#if __has_builtin(__builtin_amdgcn_exp2f)
  return __builtin_amdgcn_exp2f(x);
#else
  return exp2f(x);
#endif
}

// pack two f32 -> two f16 in one v_cvt_pkrtz; bit-cast to _Float16 vector type
__device__ __forceinline__ h2 pkrtz(float a, float b){
  fp16x2 t = __builtin_amdgcn_cvt_pkrtz(a, b);
  h2 r; __builtin_memcpy(&r, &t, 4);
  return r;
}

// ---------------- fused fp32 -> fp16 convert (x, w1, w2 in one launch) ----------------
#define NA4 1572864
#define NB4 442368
#define NC4 147456
__global__ __launch_bounds__(256) void cvt3_kernel(
    const float* __restrict__ a, u16* __restrict__ da,
    const float* __restrict__ b, u16* __restrict__ db,
    const float* __restrict__ c, u16* __restrict__ dc)
{
  int i = blockIdx.x*256 + threadIdx.x;
  const float* s; u16* d; int off;
  if (i < NA4)            { s = a; d = da; off = i; }
  else if (i < NA4+NB4)   { s = b; d = db; off = i - NA4; }
  else if (i < NA4+NB4+NC4){ s = c; d = dc; off = i - NA4 - NB4; }
  else return;
  f32x4 v = ((const f32x4*)s)[off];
  u16x4 o;
  o[0]=f2h(v[0]); o[1]=f2h(v[1]); o[2]=f2h(v[2]); o[3]=f2h(v[3]);
  ((u16x4*)d)[off] = o;
}

// ---------------- fp16 GEMM, C = A(M x 768) * B(N x 768)^T + bias ----------------
// Single-buffer 2-barrier loop, BK=64: half the barrier/vmcnt(0) drains of BK=32
// (12 vs 24), 32 MFMA per drain. LDS 2x16KB -> still 4 blocks/CU (VGPR-capped).
// 128B LDS rows make bank-swizzle effective (row bits now reach the bank bits):
// LDS slot c of row r holds global 16B-slot c ^ (r&7); staged via pre-swizzled
// GLOBAL source (linear LDS dest, rule: both-sides-or-neither), read back with
// slot = (hi + 4*kk) ^ (lo&7)  ->  8 start banks x 2 lanes = 2-way (free).
// mode 0: fused q/k row-normalize (+ logit_scale*log2e on q) and scatter into
//         q/k/v head buffers (N,H,L,D) fp16.  mode 1: fp32 out (M x 768).
__global__ __launch_bounds__(256) void gemm_kernel(
    const u16* __restrict__ A, const u16* __restrict__ B, const float* __restrict__ bias,
    int mode, u16* __restrict__ qh, u16* __restrict__ kh, u16* __restrict__ vh,
    float* __restrict__ outp, const float* __restrict__ lsb)
{
  __shared__ u16 lA[128*64];   // [row(128)][slot(8) of 16B], swizzled slots
  __shared__ u16 lB[128*64];
  const int tid = threadIdx.x;
  const int lane = tid & 63;
  const int w = tid >> 6, wr = w >> 1, wc = w & 1;
  const int lo = lane & 15, hi = lane >> 4;

  const int bx = blockIdx.x, by = blockIdx.y;

  f32x4 zero = {0.f,0.f,0.f,0.f};
  f32x4 acc[4][4];
#pragma unroll
  for (int a=0;a<4;a++)
#pragma unroll
    for (int b=0;b<4;b++) acc[a][b] = zero;
  const u16* Ag = A + (size_t)bx*128*768;
  const u16* Bg = B + (size_t)by*128*768;
  const int srow = tid >> 3;                         // 0..31 (+j*32)
  const int scol = (((tid & 7) ^ (srow & 7)) * 8);   // pre-swizzled source 16B-slot

  for (int kt = 0; kt < 768; kt += 64) {
#pragma unroll
    for (int j=0;j<4;j++) {
      __builtin_amdgcn_global_load_lds((gas_u16*)(Ag + (size_t)(j*32+srow)*768 + kt + scol), (las_u16*)(lA + j*2048 + tid*8), 16, 0, 0);
      __builtin_amdgcn_global_load_lds((gas_u16*)(Bg + (size_t)(j*32+srow)*768 + kt + scol), (las_u16*)(lB + j*2048 + tid*8), 16, 0, 0);
    }
    __syncthreads();
#pragma unroll
    for (int kk=0;kk<2;kk++) {
      h8 af[4], bfr[4];
#pragma unroll
      for (int mf=0; mf<4; mf++) {
        int r = wr*64 + mf*16 + lo;
        af[mf]  = *(const h8*)(lA + r*64 + (((hi + 4*kk) ^ (lo & 7)) * 8));
      }
#pragma unroll
      for (int nf=0; nf<4; nf++) {
        int r = wc*64 + nf*16 + lo;
        bfr[nf] = *(const h8*)(lB + r*64 + (((hi + 4*kk) ^ (lo & 7)) * 8));
      }
#pragma unroll
      for (int mf=0; mf<4; mf++)
#pragma unroll
        for (int nf=0; nf<4; nf++)
          acc[mf][nf] = MFMA32(af[mf], bfr[nf], acc[mf][nf]);
    }
    __syncthreads();
  }

  const int r0 = bx*128 + wr*64;
  const int j0 = by*128 + wc*64;
  if (mode == 0) {
    // j0 is 64-aligned and 768 % 64 == 0 -> this wc-block maps to exactly one
    // projection p and one head hh (wave-uniform).
    const int p = (j0 >= 1536) ? 2 : ((j0 >= 768) ? 1 : 0);
    const int c0 = j0 - p*768;
    const int hh = c0 >> 6;
    u16* dst = (p==0) ? qh : ((p==1) ? kh : vh);
    float bi[4];
#pragma unroll
    for (int nf=0;nf<4;nf++) bi[nf] = bias[j0 + nf*16 + lo];
    float qsc = 1.0f;
    if (p == 0) qsc = __expf(fminf(lsb[hh], 4.6051701859880913680f)) * 1.4426950408889634f;
    const bool dnorm = (p != 2);
#pragma unroll
    for (int mf=0; mf<4; mf++)
#pragma unroll
      for (int i=0;i<4;i++) {
        int r = r0 + mf*16 + 4*hi + i;
        int n = r & 7, l = r >> 3;
        float v[4]; float ss = 0.f;
#pragma unroll
        for (int nf=0;nf<4;nf++){ v[nf] = acc[mf][nf][i] + bi[nf]; ss += v[nf]*v[nf]; }
        float sc = 1.0f;
        if (dnorm) {
          // quarter-wave (16 lanes, lo=0..15) holds the full 64-wide d row
          ss += __shfl_xor(ss, 1);
          ss += __shfl_xor(ss, 2);
          ss += __shfl_xor(ss, 4);
          ss += __shfl_xor(ss, 8);
          sc = qsc / fmaxf(sqrtf(ss), 1e-12f);
        }
        size_t base = (((size_t)n*12 + hh)*1024 + l)*64;
#pragma unroll
        for (int nf=0;nf<4;nf++)
          dst[base + nf*16 + lo] = f2h(v[nf]*sc);
      }
  } else {
#pragma unroll
    for (int nf=0; nf<4; nf++) {
      int j = j0 + nf*16 + lo;
      float bi = bias[j];
#pragma unroll
      for (int mf=0; mf<4; mf++)
#pragma unroll
        for (int i=0;i<4;i++) {
          int r = r0 + mf*16 + 4*hi + i;
          outp[(size_t)r*768 + j] = acc[mf][nf][i] + bi;
        }
    }
  }
}

// ---------------- V transpose: (N,H,L,D) -> (N,H,D,L) ----------------
__global__ __launch_bounds__(256) void transpose_kernel(const u16* __restrict__ vh, u16* __restrict__ vt){
  __shared__ u16 tile[64*72];   // [l(64)][d] padded stride 72
  const int nh = blockIdx.y, lt = blockIdx.x, tid = threadIdx.x;
  const int r = tid >> 2, c0 = (tid & 3) * 16;
  const u16* src = vh + (size_t)nh*65536 + (size_t)(lt*64 + r)*64 + c0;
  u32x4 a = *(const u32x4*)src, b = *(const u32x4*)(src + 8);
  *(u32x4*)(tile + r*72 + c0)     = a;
  *(u32x4*)(tile + r*72 + c0 + 8) = b;
  __syncthreads();
  u16x8 o0, o1;
#pragma unroll
  for (int s=0;s<8;s++){ o0[s] = tile[(c0+s)*72 + r]; o1[s] = tile[(c0+8+s)*72 + r]; }
  u16* dst = vt + (size_t)nh*65536 + (size_t)r*1024 + lt*64 + c0;
  *(u16x8*)dst       = o0;
  *(u16x8*)(dst + 8) = o1;
}

// ---------------- flash attention (cosine-bounded: no running max needed) ----------------
// grid (8 q-tiles, 96 n*h), remapped so all 8 q-tiles of one (n,h) share an XCD.
// block 256 = 4 waves, each wave owns 32 q rows (two 16-row groups a/b).
// swapped QK^T: sT = mfma(Ktile, Q) -> lane holds S^T[k=kf*16+4hi+i][q=lo] in log2 units.
// Scores bounded by +-exp(min(ls,4.6))*log2e (= 14.43 here) so p = exp2(s) fits fp16
// normals with NO max subtraction / rescale. Row sums computed on the matrix pipe
// via an all-ones A-operand mfma16 (every lane ends up holding the full row sum).
// PV: C/D layout of QK^T == B-operand layout of mfma_f32_16x16x16f16, so the packed
// P fragment feeds PV directly from registers - no LDS repack.
__global__ __launch_bounds__(256) void flash_kernel(
    const u16* __restrict__ qh, const u16* __restrict__ kh, const u16* __restrict__ vt,
    u16* __restrict__ obuf, const float* __restrict__ hsv, const float* __restrict__ lsp)
{
  __shared__ u16 lK[2*64*72];    // double-buffered [k(64)][d(64)] pad 72
  __shared__ u16 lVT[2*64*72];   // double-buffered [d(64)][k(64)] pad 72
  // XCD-locality remap: linear id -> (xcd, idx); 12 heads x 8 q-tiles per XCD (3MB K+V in L2)
  const int lin = blockIdx.y*8 + blockIdx.x;
  const int xcd = lin & 7, g = lin >> 3;
  const int nh = xcd + 8*(g >> 3);
  const int qt = g & 7;
  const int h = nh % 12, n = nh / 12;
  const u16* Qp = qh + (size_t)nh*65536;
  const u16* Kp = kh + (size_t)nh*65536;
  const u16* Vp = vt + (size_t)nh*65536;
  const int tid = threadIdx.x, lane = tid & 63, w = tid >> 6;
  const int lo = lane & 15, hi = lane >> 4;

  // Q fragments for both q-groups: lane holds Q[q=lo(+16)][d = hi*8 + j]
  h8 qa0, qa1, qb0, qb1;
  {
    const u16* qrow = Qp + (size_t)(qt*128 + w*32 + lo)*64 + hi*8;
    qa0 = *(const h8*)qrow;          qa1 = *(const h8*)(qrow + 32);
    qb0 = *(const h8*)(qrow + 1024); qb1 = *(const h8*)(qrow + 1024 + 32);
  }
  const f32x4 zero = {0.f,0.f,0.f,0.f};
  f32x4 oA[4] = {zero,zero,zero,zero};   // O^T[d=db*16+4hi+i][q=lo]
  f32x4 oB[4] = {zero,zero,zero,zero};
  f32x4 lA4 = zero, lB4 = zero;          // row sums via ones-MFMA
  const h4 ones = {(f16)1.f,(f16)1.f,(f16)1.f,(f16)1.f};

  // fp16-overflow guard (0 for these inputs; uniform branch if ever nonzero)
  float OFF;
  {
    float b = __expf(fminf(lsp[h], 4.6051701859880913680f)) * 1.4426950408889634f;
    OFF = fmaxf(b - 15.5f, 0.f);
  }

  const int sr = tid >> 2;          // stage row (k for lK, d for lVT)
  const int sc = (tid & 3) * 16;    // stage col
  u32x4 ka, kb, va, vb;
  ka = *(const u32x4*)(Kp + (size_t)sr*64 + sc);
  kb = *(const u32x4*)(Kp + (size_t)sr*64 + sc + 8);
  va = *(const u32x4*)(Vp + (size_t)sr*1024 + sc);
  vb = *(const u32x4*)(Vp + (size_t)sr*1024 + sc + 8);
  *(u32x4*)(lK  + sr*72 + sc)     = ka;
  *(u32x4*)(lK  + sr*72 + sc + 8) = kb;
  *(u32x4*)(lVT + sr*72 + sc)     = va;
  *(u32x4*)(lVT + sr*72 + sc + 8) = vb;
  __syncthreads();

  for (int t = 0; t < 16; ++t) {
    const u16* cK = lK  + (t&1)*4608;
    const u16* cV = lVT + (t&1)*4608;
    u16* nK = lK  + ((t&1)^1)*4608;
    u16* nV = lVT + ((t&1)^1)*4608;
    if (t < 15) {  // issue next-tile loads early; HBM latency hides under compute
      ka = *(const u32x4*)(Kp + (size_t)(t+1)*4096 + (size_t)sr*64 + sc);
      kb = *(const u32x4*)(Kp + (size_t)(t+1)*4096 + (size_t)sr*64 + sc + 8);
      va = *(const u32x4*)(Vp + (size_t)sr*1024 + (t+1)*64 + sc);
      vb = *(const u32x4*)(Vp + (size_t)sr*1024 + (t+1)*64 + sc + 8);
    }
    // S^T = K . Q^T for both q-groups (K fragments shared -> LDS reads amortized 2x)
    f32x4 sa[4], sb[4];
#pragma unroll
    for (int kf=0; kf<4; kf++) {
      const u16* krow = cK + (kf*16 + lo)*72 + hi*8;
      h8 k0 = *(const h8*)krow;
      h8 k1 = *(const h8*)(krow + 32);
      sa[kf] = MFMA32(k1, qa1, MFMA32(k0, qa0, zero));
      sb[kf] = MFMA32(k1, qb1, MFMA32(k0, qb0, zero));
    }
    if (OFF != 0.f) {
#pragma unroll
      for (int kf=0;kf<4;kf++)
#pragma unroll
        for (int i=0;i<4;i++) { sa[kf][i] -= OFF; sb[kf][i] -= OFF; }
    }
    // p = exp2(s), packed straight into the mfma16 B-operand layout
    h4 pa[4], pb[4];
#pragma unroll
    for (int kf=0;kf<4;kf++) {
      h2 a01 = pkrtz(fast_exp2(sa[kf][0]), fast_exp2(sa[kf][1]));
      h2 a23 = pkrtz(fast_exp2(sa[kf][2]), fast_exp2(sa[kf][3]));
      pa[kf] = __builtin_shufflevector(a01, a23, 0, 1, 2, 3);
      h2 b01 = pkrtz(fast_exp2(sb[kf][0]), fast_exp2(sb[kf][1]));
      h2 b23 = pkrtz(fast_exp2(sb[kf][2]), fast_exp2(sb[kf][3]));
      pb[kf] = __builtin_shufflevector(b01, b23, 0, 1, 2, 3);
    }
    // row sums on the matrix pipe: every lane gets the full sum for its q=lo
#pragma unroll
    for (int kf=0;kf<4;kf++) {
      lA4 = MFMA16(ones, pa[kf], lA4);
      lB4 = MFMA16(ones, pb[kf], lB4);
    }
    // PV: O^T += VT-frag x P-frag, K=16 MFMAs, V fragments shared across q-groups
#pragma unroll
    for (int db=0; db<4; db++) {
#pragma unroll
      for (int kf=0; kf<4; kf++) {
        h4 vf = *(const h4*)(cV + (db*16 + lo)*72 + kf*16 + hi*4);
        oA[db] = MFMA16(vf, pa[kf], oA[db]);
        oB[db] = MFMA16(vf, pb[kf], oB[db]);
      }
    }
    if (t < 15) {  // write next tile into the other buffer; single barrier per iter
      *(u32x4*)(nK + sr*72 + sc)     = ka;
      *(u32x4*)(nK + sr*72 + sc + 8) = kb;
      *(u32x4*)(nV + sr*72 + sc)     = va;
      *(u32x4*)(nV + sr*72 + sc + 8) = vb;
    }
    __syncthreads();
  }
  // epilogue: O[q][d] = O^T / l * head_scale, store fp16 into (L,N,C)
  float hsc = hsv[h];
  float invA = hsc / lA4[0];
  float invB = hsc / lB4[0];
  int l0 = qt*128 + w*32 + lo;
  u16* dA = obuf + ((size_t)l0*8 + n)*768 + h*64;
  u16* dB = obuf + ((size_t)(l0+16)*8 + n)*768 + h*64;
#pragma unroll
  for (int db=0; db<4; db++) {
    u16x4 pk0, pk1;
#pragma unroll
    for (int i=0;i<4;i++) { pk0[i] = f2h(oA[db][i]*invA); pk1[i] = f2h(oB[db][i]*invB); }
    *(u16x4*)(dA + db*16 + hi*4) = pk0;
    *(u16x4*)(dB + db*16 + hi*4) = pk1;
  }
}

extern "C" void kernel_launch(void* const* d_in, const int* in_sizes, int n_in,
                              void* d_out, int out_size, void* d_ws, size_t ws_size,
                              hipStream_t stream)
{
  (void)in_sizes; (void)n_in; (void)out_size; (void)ws_size;
  const float* x  = (const float*)d_in[0];
  const float* w1 = (const float*)d_in[1];
  const float* b1 = (const float*)d_in[2];
  const float* ls = (const float*)d_in[3];
  const float* hs = (const float*)d_in[4];
  const float* w2 = (const float*)d_in[5];
  const float* b2 = (const float*)d_in[6];
  float* out = (float*)d_out;

  u16* x_bf  = (u16*)d_ws;            // 8192 x 768  (reused as ob after GEMM1)
  u16* w1_bf = x_bf  + 6291456;       // 2304 x 768
  u16* w2_bf = w1_bf + 1769472;       // 768 x 768
  u16* qh    = w2_bf + 589824;        // (N,H,L,D) normalized (+ls*log2e on q)
  u16* kh    = qh    + 6291456;
  u16* vh    = kh    + 6291456;
  u16* vt    = vh    + 6291456;       // (N,H,D,L)
  u16* ob    = x_bf;                  // (L,N,C) fp16, aliases x_bf

  cvt3_kernel<<<8448, 256, 0, stream>>>(x, x_bf, w1, w1_bf, w2, w2_bf);
  gemm_kernel<<<dim3(64,18), 256, 0, stream>>>(x_bf, w1_bf, b1, 0, qh, kh, vh, nullptr, ls);
  transpose_kernel<<<dim3(16,96), 256, 0, stream>>>(vh, vt);
  flash_kernel<<<dim3(8,96), 256, 0, stream>>>(qh, kh, vt, ob, hs, ls);
  gemm_kernel<<<dim3(64,6), 256, 0, stream>>>(ob, w2_bf, b2, 1, nullptr, nullptr, nullptr, out, ls);
}

// Round 7
// 130.601 us; speedup vs baseline: 1.1837x; 1.0633x over previous
//
#include <hip/hip_runtime.h>
#include <stdint.h>
#include <math.h>

typedef unsigned short u16;
typedef _Float16 f16;
typedef __attribute__((ext_vector_type(4))) float f32x4;
typedef __attribute__((ext_vector_type(8))) f16 h8;
typedef __attribute__((ext_vector_type(4))) f16 h4;
typedef __attribute__((ext_vector_type(2))) f16 h2;
typedef __attribute__((ext_vector_type(2))) __fp16 fp16x2;
typedef __attribute__((ext_vector_type(4))) unsigned int u32x4;
typedef __attribute__((ext_vector_type(4))) unsigned short u16x4;
typedef __attribute__((ext_vector_type(8))) unsigned short u16x8;

typedef const __attribute__((address_space(1))) u16 gas_u16;
typedef __attribute__((address_space(3))) u16 las_u16;

#define MFMA32(a,b,c) __builtin_amdgcn_mfma_f32_16x16x32_f16((a),(b),(c),0,0,0)
#define MFMA16(a,b,c) __builtin_amdgcn_mfma_f32_16x16x16f16((a),(b),(c),0,0,0)

__device__ __forceinline__ float h2f(u16 h){ f16 x; __builtin_memcpy(&x,&h,2); return (float)x; }
__device__ __forceinline__ u16 f2h(float f){ f16 x = (f16)f; u16 u; __builtin_memcpy(&u,&x,2); return u; }

__device__ __forceinline__ float fast_exp2(float x){
#if __has_builtin(__builtin_amdgcn_exp2f)
  return __builtin_amdgcn_exp2f(x);
#else
  return exp2f(x);
#endif
}

// pack two f32 -> two f16 in one v_cvt_pkrtz; bit-cast to _Float16 vector type
__device__ __forceinline__ h2 pkrtz(float a, float b){
  fp16x2 t = __builtin_amdgcn_cvt_pkrtz(a, b);
  h2 r; __builtin_memcpy(&r, &t, 4);
  return r;
}

// ---------------- fused fp32 -> fp16 convert (x, w1, w2 in one launch) ----------------
#define NA4 1572864
#define NB4 442368
#define NC4 147456
__global__ __launch_bounds__(256) void cvt3_kernel(
    const float* __restrict__ a, u16* __restrict__ da,
    const float* __restrict__ b, u16* __restrict__ db,
    const float* __restrict__ c, u16* __restrict__ dc)
{
  int i = blockIdx.x*256 + threadIdx.x;
  const float* s; u16* d; int off;
  if (i < NA4)            { s = a; d = da; off = i; }
  else if (i < NA4+NB4)   { s = b; d = db; off = i - NA4; }
  else if (i < NA4+NB4+NC4){ s = c; d = dc; off = i - NA4 - NB4; }
  else return;
  f32x4 v = ((const f32x4*)s)[off];
  u16x4 o;
  o[0]=f2h(v[0]); o[1]=f2h(v[1]); o[2]=f2h(v[2]); o[3]=f2h(v[3]);
  ((u16x4*)d)[off] = o;
}

// ---------------- fp16 GEMM, C = A(M x 768) * B(N x 768)^T + bias ----------------
// T4 counted-vmcnt double-buffered pipeline (BK=64, 12 K-steps):
//   STAGE(next tile, 8 x global_load_lds) -> s_waitcnt vmcnt(8)  [waits ONLY the
//   current tile's loads; next tile's 8 stay in flight ACROSS the barrier] ->
//   raw s_barrier (no implicit vmcnt(0) drain, unlike __syncthreads) ->
//   ds_read+MFMA -> lgkmcnt(0)+sched_barrier -> s_barrier.
// WAR safe: reads of the buffer being restaged were drained by the PREVIOUS
// iteration's lgkmcnt(0)+barrier. LDS 64KB -> 2 blocks/CU; the pipeline (not
// occupancy) hides latency.
// Bank swizzle (verified 0 conflicts, round 6): LDS slot c of row r holds global
// 16B-slot c ^ (r&7); pre-swizzled GLOBAL source + same XOR on ds_read side.
// mode 0: fused q/k row-normalize (+ logit_scale*log2e on q) and scatter into
//         q/k/v head buffers (N,H,L,D) fp16.  mode 1: fp32 out (M x 768).
__global__ __launch_bounds__(256) void gemm_kernel(
    const u16* __restrict__ A, const u16* __restrict__ B, const float* __restrict__ bias,
    int mode, u16* __restrict__ qh, u16* __restrict__ kh, u16* __restrict__ vh,
    float* __restrict__ outp, const float* __restrict__ lsb)
{
  __shared__ u16 lA[2][128*64];   // [buf][row(128)][slot(8) of 16B], swizzled slots
  __shared__ u16 lB[2][128*64];
  const int tid = threadIdx.x;
  const int lane = tid & 63;
  const int w = tid >> 6, wr = w >> 1, wc = w & 1;
  const int lo = lane & 15, hi = lane >> 4;

  const int bx = blockIdx.x, by = blockIdx.y;

  f32x4 zero = {0.f,0.f,0.f,0.f};
  f32x4 acc[4][4];
#pragma unroll
  for (int a=0;a<4;a++)
#pragma unroll
    for (int b=0;b<4;b++) acc[a][b] = zero;
  const u16* Ag = A + (size_t)bx*128*768;
  const u16* Bg = B + (size_t)by*128*768;
  const int srow = tid >> 3;                         // 0..31 (+j*32)
  const int scol = (((tid & 7) ^ (srow & 7)) * 8);   // pre-swizzled source 16B-slot

#define STAGE(buf, kt) do { \
    _Pragma("unroll") \
    for (int j=0;j<4;j++) { \
      __builtin_amdgcn_global_load_lds((gas_u16*)(Ag + (size_t)(j*32+srow)*768 + (kt) + scol), (las_u16*)(&lA[buf][j*2048 + tid*8]), 16, 0, 0); \
      __builtin_amdgcn_global_load_lds((gas_u16*)(Bg + (size_t)(j*32+srow)*768 + (kt) + scol), (las_u16*)(&lB[buf][j*2048 + tid*8]), 16, 0, 0); \
    } \
  } while(0)

  STAGE(0, 0);
#pragma unroll
  for (int t = 0; t < 12; ++t) {
    const int cur = t & 1;
    if (t < 11) {
      STAGE(cur^1, (t+1)*64);                         // next tile: 8 loads in flight
      asm volatile("s_waitcnt vmcnt(8)" ::: "memory"); // current tile landed
    } else {
      asm volatile("s_waitcnt vmcnt(0)" ::: "memory");
    }
    __builtin_amdgcn_sched_barrier(0);
    __builtin_amdgcn_s_barrier();                     // no implicit drain
#pragma unroll
    for (int kk=0;kk<2;kk++) {
      h8 af[4], bfr[4];
#pragma unroll
      for (int mf=0; mf<4; mf++) {
        int r = wr*64 + mf*16 + lo;
        af[mf]  = *(const h8*)(&lA[cur][r*64 + (((hi + 4*kk) ^ (lo & 7)) * 8)]);
      }
#pragma unroll
      for (int nf=0; nf<4; nf++) {
        int r = wc*64 + nf*16 + lo;
        bfr[nf] = *(const h8*)(&lB[cur][r*64 + (((hi + 4*kk) ^ (lo & 7)) * 8)]);
      }
#pragma unroll
      for (int mf=0; mf<4; mf++)
#pragma unroll
        for (int nf=0; nf<4; nf++)
          acc[mf][nf] = MFMA32(af[mf], bfr[nf], acc[mf][nf]);
    }
    asm volatile("s_waitcnt lgkmcnt(0)" ::: "memory"); // my reads of cur retired
    __builtin_amdgcn_sched_barrier(0);
    __builtin_amdgcn_s_barrier();                      // now cur may be restaged
  }
#undef STAGE

  const int r0 = bx*128 + wr*64;
  const int j0 = by*128 + wc*64;
  if (mode == 0) {
    // j0 is 64-aligned and 768 % 64 == 0 -> this wc-block maps to exactly one
    // projection p and one head hh (wave-uniform).
    const int p = (j0 >= 1536) ? 2 : ((j0 >= 768) ? 1 : 0);
    const int c0 = j0 - p*768;
    const int hh = c0 >> 6;
    u16* dst = (p==0) ? qh : ((p==1) ? kh : vh);
    float bi[4];
#pragma unroll
    for (int nf=0;nf<4;nf++) bi[nf] = bias[j0 + nf*16 + lo];
    float qsc = 1.0f;
    if (p == 0) qsc = __expf(fminf(lsb[hh], 4.6051701859880913680f)) * 1.4426950408889634f;
    const bool dnorm = (p != 2);
#pragma unroll
    for (int mf=0; mf<4; mf++)
#pragma unroll
      for (int i=0;i<4;i++) {
        int r = r0 + mf*16 + 4*hi + i;
        int n = r & 7, l = r >> 3;
        float v[4]; float ss = 0.f;
#pragma unroll
        for (int nf=0;nf<4;nf++){ v[nf] = acc[mf][nf][i] + bi[nf]; ss += v[nf]*v[nf]; }
        float sc = 1.0f;
        if (dnorm) {
          // quarter-wave (16 lanes, lo=0..15) holds the full 64-wide d row
          ss += __shfl_xor(ss, 1);
          ss += __shfl_xor(ss, 2);
          ss += __shfl_xor(ss, 4);
          ss += __shfl_xor(ss, 8);
          sc = qsc / fmaxf(sqrtf(ss), 1e-12f);
        }
        size_t base = (((size_t)n*12 + hh)*1024 + l)*64;
#pragma unroll
        for (int nf=0;nf<4;nf++)
          dst[base + nf*16 + lo] = f2h(v[nf]*sc);
      }
  } else {
#pragma unroll
    for (int nf=0; nf<4; nf++) {
      int j = j0 + nf*16 + lo;
      float bi = bias[j];
#pragma unroll
      for (int mf=0; mf<4; mf++)
#pragma unroll
        for (int i=0;i<4;i++) {
          int r = r0 + mf*16 + 4*hi + i;
          outp[(size_t)r*768 + j] = acc[mf][nf][i] + bi;
        }
    }
  }
}

// ---------------- V transpose: (N,H,L,D) -> (N,H,D,L) ----------------
__global__ __launch_bounds__(256) void transpose_kernel(const u16* __restrict__ vh, u16* __restrict__ vt){
  __shared__ u16 tile[64*72];   // [l(64)][d] padded stride 72
  const int nh = blockIdx.y, lt = blockIdx.x, tid = threadIdx.x;
  const int r = tid >> 2, c0 = (tid & 3) * 16;
  const u16* src = vh + (size_t)nh*65536 + (size_t)(lt*64 + r)*64 + c0;
  u32x4 a = *(const u32x4*)src, b = *(const u32x4*)(src + 8);
  *(u32x4*)(tile + r*72 + c0)     = a;
  *(u32x4*)(tile + r*72 + c0 + 8) = b;
  __syncthreads();
  u16x8 o0, o1;
#pragma unroll
  for (int s=0;s<8;s++){ o0[s] = tile[(c0+s)*72 + r]; o1[s] = tile[(c0+8+s)*72 + r]; }
  u16* dst = vt + (size_t)nh*65536 + (size_t)r*1024 + lt*64 + c0;
  *(u16x8*)dst       = o0;
  *(u16x8*)(dst + 8) = o1;
}

// ---------------- flash attention (cosine-bounded: no running max needed) ----------------
// grid (8 q-tiles, 96 n*h), remapped so all 8 q-tiles of one (n,h) share an XCD.
// block 256 = 4 waves, each wave owns 32 q rows (two 16-row groups a/b).
// swapped QK^T: sT = mfma(Ktile, Q) -> lane holds S^T[k=kf*16+4hi+i][q=lo] in log2 units.
// Scores bounded by +-exp(min(ls,4.6))*log2e (= 14.43 here) so p = exp2(s) fits fp16
// normals with NO max subtraction / rescale. Row sums computed on the matrix pipe
// via an all-ones A-operand mfma16 (every lane ends up holding the full row sum).
// PV: C/D layout of QK^T == B-operand layout of mfma_f32_16x16x16f16, so the packed
// P fragment feeds PV directly from registers - no LDS repack.
__global__ __launch_bounds__(256) void flash_kernel(
    const u16* __restrict__ qh, const u16* __restrict__ kh, const u16* __restrict__ vt,
    u16* __restrict__ obuf, const float* __restrict__ hsv, const float* __restrict__ lsp)
{
  __shared__ u16 lK[2*64*72];    // double-buffered [k(64)][d(64)] pad 72
  __shared__ u16 lVT[2*64*72];   // double-buffered [d(64)][k(64)] pad 72
  // XCD-locality remap: linear id -> (xcd, idx); 12 heads x 8 q-tiles per XCD (3MB K+V in L2)
  const int lin = blockIdx.y*8 + blockIdx.x;
  const int xcd = lin & 7, g = lin >> 3;
  const int nh = xcd + 8*(g >> 3);
  const int qt = g & 7;
  const int h = nh % 12, n = nh / 12;
  const u16* Qp = qh + (size_t)nh*65536;
  const u16* Kp = kh + (size_t)nh*65536;
  const u16* Vp = vt + (size_t)nh*65536;
  const int tid = threadIdx.x, lane = tid & 63, w = tid >> 6;
  const int lo = lane & 15, hi = lane >> 4;

  // Q fragments for both q-groups: lane holds Q[q=lo(+16)][d = hi*8 + j]
  h8 qa0, qa1, qb0, qb1;
  {
    const u16* qrow = Qp + (size_t)(qt*128 + w*32 + lo)*64 + hi*8;
    qa0 = *(const h8*)qrow;          qa1 = *(const h8*)(qrow + 32);
    qb0 = *(const h8*)(qrow + 1024); qb1 = *(const h8*)(qrow + 1024 + 32);
  }
  const f32x4 zero = {0.f,0.f,0.f,0.f};
  f32x4 oA[4] = {zero,zero,zero,zero};   // O^T[d=db*16+4hi+i][q=lo]
  f32x4 oB[4] = {zero,zero,zero,zero};
  f32x4 lA4 = zero, lB4 = zero;          // row sums via ones-MFMA
  const h4 ones = {(f16)1.f,(f16)1.f,(f16)1.f,(f16)1.f};

  // fp16-overflow guard (0 for these inputs; uniform branch if ever nonzero)
  float OFF;
  {
    float b = __expf(fminf(lsp[h], 4.6051701859880913680f)) * 1.4426950408889634f;
    OFF = fmaxf(b - 15.5f, 0.f);
  }

  const int sr = tid >> 2;          // stage row (k for lK, d for lVT)
  const int sc = (tid & 3) * 16;    // stage col
  u32x4 ka, kb, va, vb;
  ka = *(const u32x4*)(Kp + (size_t)sr*64 + sc);
  kb = *(const u32x4*)(Kp + (size_t)sr*64 + sc + 8);
  va = *(const u32x4*)(Vp + (size_t)sr*1024 + sc);
  vb = *(const u32x4*)(Vp + (size_t)sr*1024 + sc + 8);
  *(u32x4*)(lK  + sr*72 + sc)     = ka;
  *(u32x4*)(lK  + sr*72 + sc + 8) = kb;
  *(u32x4*)(lVT + sr*72 + sc)     = va;
  *(u32x4*)(lVT + sr*72 + sc + 8) = vb;
  __syncthreads();

  for (int t = 0; t < 16; ++t) {
    const u16* cK = lK  + (t&1)*4608;
    const u16* cV = lVT + (t&1)*4608;
    u16* nK = lK  + ((t&1)^1)*4608;
    u16* nV = lVT + ((t&1)^1)*4608;
    if (t < 15) {  // issue next-tile loads early; HBM latency hides under compute
      ka = *(const u32x4*)(Kp + (size_t)(t+1)*4096 + (size_t)sr*64 + sc);
      kb = *(const u32x4*)(Kp + (size_t)(t+1)*4096 + (size_t)sr*64 + sc + 8);
      va = *(const u32x4*)(Vp + (size_t)sr*1024 + (t+1)*64 + sc);
      vb = *(const u32x4*)(Vp + (size_t)sr*1024 + (t+1)*64 + sc + 8);
    }
    // S^T = K . Q^T for both q-groups (K fragments shared -> LDS reads amortized 2x)
    f32x4 sa[4], sb[4];
#pragma unroll
    for (int kf=0; kf<4; kf++) {
      const u16* krow = cK + (kf*16 + lo)*72 + hi*8;
      h8 k0 = *(const h8*)krow;
      h8 k1 = *(const h8*)(krow + 32);
      sa[kf] = MFMA32(k1, qa1, MFMA32(k0, qa0, zero));
      sb[kf] = MFMA32(k1, qb1, MFMA32(k0, qb0, zero));
    }
    if (OFF != 0.f) {
#pragma unroll
      for (int kf=0;kf<4;kf++)
#pragma unroll
        for (int i=0;i<4;i++) { sa[kf][i] -= OFF; sb[kf][i] -= OFF; }
    }
    // p = exp2(s), packed straight into the mfma16 B-operand layout
    h4 pa[4], pb[4];
#pragma unroll
    for (int kf=0;kf<4;kf++) {
      h2 a01 = pkrtz(fast_exp2(sa[kf][0]), fast_exp2(sa[kf][1]));
      h2 a23 = pkrtz(fast_exp2(sa[kf][2]), fast_exp2(sa[kf][3]));
      pa[kf] = __builtin_shufflevector(a01, a23, 0, 1, 2, 3);
      h2 b01 = pkrtz(fast_exp2(sb[kf][0]), fast_exp2(sb[kf][1]));
      h2 b23 = pkrtz(fast_exp2(sb[kf][2]), fast_exp2(sb[kf][3]));
      pb[kf] = __builtin_shufflevector(b01, b23, 0, 1, 2, 3);
    }
    // row sums on the matrix pipe: every lane gets the full sum for its q=lo
#pragma unroll
    for (int kf=0;kf<4;kf++) {
      lA4 = MFMA16(ones, pa[kf], lA4);
      lB4 = MFMA16(ones, pb[kf], lB4);
    }
    // PV: O^T += VT-frag x P-frag, K=16 MFMAs, V fragments shared across q-groups
#pragma unroll
    for (int db=0; db<4; db++) {
#pragma unroll
      for (int kf=0; kf<4; kf++) {
        h4 vf = *(const h4*)(cV + (db*16 + lo)*72 + kf*16 + hi*4);
        oA[db] = MFMA16(vf, pa[kf], oA[db]);
        oB[db] = MFMA16(vf, pb[kf], oB[db]);
      }
    }
    if (t < 15) {  // write next tile into the other buffer; single barrier per iter
      *(u32x4*)(nK + sr*72 + sc)     = ka;
      *(u32x4*)(nK + sr*72 + sc + 8) = kb;
      *(u32x4*)(nV + sr*72 + sc)     = va;
      *(u32x4*)(nV + sr*72 + sc + 8) = vb;
    }
    __syncthreads();
  }
  // epilogue: O[q][d] = O^T / l * head_scale, store fp16 into (L,N,C)
  float hsc = hsv[h];
  float invA = hsc / lA4[0];
  float invB = hsc / lB4[0];
  int l0 = qt*128 + w*32 + lo;
  u16* dA = obuf + ((size_t)l0*8 + n)*768 + h*64;
  u16* dB = obuf + ((size_t)(l0+16)*8 + n)*768 + h*64;
#pragma unroll
  for (int db=0; db<4; db++) {
    u16x4 pk0, pk1;
#pragma unroll
    for (int i=0;i<4;i++) { pk0[i] = f2h(oA[db][i]*invA); pk1[i] = f2h(oB[db][i]*invB); }
    *(u16x4*)(dA + db*16 + hi*4) = pk0;
    *(u16x4*)(dB + db*16 + hi*4) = pk1;
  }
}

extern "C" void kernel_launch(void* const* d_in, const int* in_sizes, int n_in,
                              void* d_out, int out_size, void* d_ws, size_t ws_size,
                              hipStream_t stream)
{
  (void)in_sizes; (void)n_in; (void)out_size; (void)ws_size;
  const float* x  = (const float*)d_in[0];
  const float* w1 = (const float*)d_in[1];
  const float* b1 = (const float*)d_in[2];
  const float* ls = (const float*)d_in[3];
  const float* hs = (const float*)d_in[4];
  const float* w2 = (const float*)d_in[5];
  const float* b2 = (const float*)d_in[6];
  float* out = (float*)d_out;

  u16* x_bf  = (u16*)d_ws;            // 8192 x 768  (reused as ob after GEMM1)
  u16* w1_bf = x_bf  + 6291456;       // 2304 x 768
  u16* w2_bf = w1_bf + 1769472;       // 768 x 768
  u16* qh    = w2_bf + 589824;        // (N,H,L,D) normalized (+ls*log2e on q)
  u16* kh    = qh    + 6291456;
  u16* vh    = kh    + 6291456;
  u16* vt    = vh    + 6291456;       // (N,H,D,L)
  u16* ob    = x_bf;                  // (L,N,C) fp16, aliases x_bf

  cvt3_kernel<<<8448, 256, 0, stream>>>(x, x_bf, w1, w1_bf, w2, w2_bf);
  gemm_kernel<<<dim3(64,18), 256, 0, stream>>>(x_bf, w1_bf, b1, 0, qh, kh, vh, nullptr, ls);
  transpose_kernel<<<dim3(16,96), 256, 0, stream>>>(vh, vt);
  flash_kernel<<<dim3(8,96), 256, 0, stream>>>(qh, kh, vt, ob, hs, ls);
  gemm_kernel<<<dim3(64,6), 256, 0, stream>>>(ob, w2_bf, b2, 1, nullptr, nullptr, nullptr, out, ls);
}

// Round 8
// 126.016 us; speedup vs baseline: 1.2268x; 1.0364x over previous
//
#include <hip/hip_runtime.h>
#include <stdint.h>
#include <math.h>

typedef unsigned short u16;
typedef _Float16 f16;
typedef __attribute__((ext_vector_type(4))) float f32x4;
typedef __attribute__((ext_vector_type(8))) f16 h8;
typedef __attribute__((ext_vector_type(4))) f16 h4;
typedef __attribute__((ext_vector_type(2))) f16 h2;
typedef __attribute__((ext_vector_type(2))) __fp16 fp16x2;
typedef __attribute__((ext_vector_type(2))) unsigned int u32x2;
typedef __attribute__((ext_vector_type(4))) unsigned int u32x4;
typedef __attribute__((ext_vector_type(4))) unsigned short u16x4;
typedef __attribute__((ext_vector_type(8))) unsigned short u16x8;

typedef const __attribute__((address_space(1))) u16 gas_u16;
typedef __attribute__((address_space(3))) u16 las_u16;

#define MFMA32(a,b,c) __builtin_amdgcn_mfma_f32_16x16x32_f16((a),(b),(c),0,0,0)
#define MFMA16(a,b,c) __builtin_amdgcn_mfma_f32_16x16x16f16((a),(b),(c),0,0,0)

__device__ __forceinline__ float h2f(u16 h){ f16 x; __builtin_memcpy(&x,&h,2); return (float)x; }
__device__ __forceinline__ u16 f2h(float f){ f16 x = (f16)f; u16 u; __builtin_memcpy(&u,&x,2); return u; }

__device__ __forceinline__ float fast_exp2(float x){
#if __has_builtin(__builtin_amdgcn_exp2f)
  return __builtin_amdgcn_exp2f(x);
#else
  return exp2f(x);
#endif
}

// pack two f32 -> two f16 in one v_cvt_pkrtz; bit-cast to _Float16 vector type
__device__ __forceinline__ h2 pkrtz(float a, float b){
  fp16x2 t = __builtin_amdgcn_cvt_pkrtz(a, b);
  h2 r; __builtin_memcpy(&r, &t, 4);
  return r;
}

// ---------------- fused fp32 -> fp16 convert (x, w1, w2 in one launch) ----------------
#define NA4 1572864
#define NB4 442368
#define NC4 147456
__global__ __launch_bounds__(256) void cvt3_kernel(
    const float* __restrict__ a, u16* __restrict__ da,
    const float* __restrict__ b, u16* __restrict__ db,
    const float* __restrict__ c, u16* __restrict__ dc)
{
  int i = blockIdx.x*256 + threadIdx.x;
  const float* s; u16* d; int off;
  if (i < NA4)            { s = a; d = da; off = i; }
  else if (i < NA4+NB4)   { s = b; d = db; off = i - NA4; }
  else if (i < NA4+NB4+NC4){ s = c; d = dc; off = i - NA4 - NB4; }
  else return;
  f32x4 v = ((const f32x4*)s)[off];
  u16x4 o;
  o[0]=f2h(v[0]); o[1]=f2h(v[1]); o[2]=f2h(v[2]); o[3]=f2h(v[3]);
  ((u16x4*)d)[off] = o;
}

// ---------------- fp16 GEMM, C = A(M x 768) * B(N x 768)^T + bias ----------------
// T4 counted-vmcnt double-buffered pipeline (BK=64, 12 K-steps). See round-7 notes.
__global__ __launch_bounds__(256) void gemm_kernel(
    const u16* __restrict__ A, const u16* __restrict__ B, const float* __restrict__ bias,
    int mode, u16* __restrict__ qh, u16* __restrict__ kh, u16* __restrict__ vh,
    float* __restrict__ outp, const float* __restrict__ lsb)
{
  __shared__ u16 lA[2][128*64];   // [buf][row(128)][slot(8) of 16B], swizzled slots
  __shared__ u16 lB[2][128*64];
  const int tid = threadIdx.x;
  const int lane = tid & 63;
  const int w = tid >> 6, wr = w >> 1, wc = w & 1;
  const int lo = lane & 15, hi = lane >> 4;

  const int bx = blockIdx.x, by = blockIdx.y;

  f32x4 zero = {0.f,0.f,0.f,0.f};
  f32x4 acc[4][4];
#pragma unroll
  for (int a=0;a<4;a++)
#pragma unroll
    for (int b=0;b<4;b++) acc[a][b] = zero;
  const u16* Ag = A + (size_t)bx*128*768;
  const u16* Bg = B + (size_t)by*128*768;
  const int srow = tid >> 3;                         // 0..31 (+j*32)
  const int scol = (((tid & 7) ^ (srow & 7)) * 8);   // pre-swizzled source 16B-slot

#define STAGE(buf, kt) do { \
    _Pragma("unroll") \
    for (int j=0;j<4;j++) { \
      __builtin_amdgcn_global_load_lds((gas_u16*)(Ag + (size_t)(j*32+srow)*768 + (kt) + scol), (las_u16*)(&lA[buf][j*2048 + tid*8]), 16, 0, 0); \
      __builtin_amdgcn_global_load_lds((gas_u16*)(Bg + (size_t)(j*32+srow)*768 + (kt) + scol), (las_u16*)(&lB[buf][j*2048 + tid*8]), 16, 0, 0); \
    } \
  } while(0)

  STAGE(0, 0);
#pragma unroll
  for (int t = 0; t < 12; ++t) {
    const int cur = t & 1;
    if (t < 11) {
      STAGE(cur^1, (t+1)*64);                         // next tile: 8 loads in flight
      asm volatile("s_waitcnt vmcnt(8)" ::: "memory"); // current tile landed
    } else {
      asm volatile("s_waitcnt vmcnt(0)" ::: "memory");
    }
    __builtin_amdgcn_sched_barrier(0);
    __builtin_amdgcn_s_barrier();                     // no implicit drain
#pragma unroll
    for (int kk=0;kk<2;kk++) {
      h8 af[4], bfr[4];
#pragma unroll
      for (int mf=0; mf<4; mf++) {
        int r = wr*64 + mf*16 + lo;
        af[mf]  = *(const h8*)(&lA[cur][r*64 + (((hi + 4*kk) ^ (lo & 7)) * 8)]);
      }
#pragma unroll
      for (int nf=0; nf<4; nf++) {
        int r = wc*64 + nf*16 + lo;
        bfr[nf] = *(const h8*)(&lB[cur][r*64 + (((hi + 4*kk) ^ (lo & 7)) * 8)]);
      }
#pragma unroll
      for (int mf=0; mf<4; mf++)
#pragma unroll
        for (int nf=0; nf<4; nf++)
          acc[mf][nf] = MFMA32(af[mf], bfr[nf], acc[mf][nf]);
    }
    asm volatile("s_waitcnt lgkmcnt(0)" ::: "memory"); // my reads of cur retired
    __builtin_amdgcn_sched_barrier(0);
    __builtin_amdgcn_s_barrier();                      // now cur may be restaged
  }
#undef STAGE

  const int r0 = bx*128 + wr*64;
  const int j0 = by*128 + wc*64;
  if (mode == 0) {
    const int p = (j0 >= 1536) ? 2 : ((j0 >= 768) ? 1 : 0);
    const int c0 = j0 - p*768;
    const int hh = c0 >> 6;
    u16* dst = (p==0) ? qh : ((p==1) ? kh : vh);
    float bi[4];
#pragma unroll
    for (int nf=0;nf<4;nf++) bi[nf] = bias[j0 + nf*16 + lo];
    float qsc = 1.0f;
    if (p == 0) qsc = __expf(fminf(lsb[hh], 4.6051701859880913680f)) * 1.4426950408889634f;
    const bool dnorm = (p != 2);
#pragma unroll
    for (int mf=0; mf<4; mf++)
#pragma unroll
      for (int i=0;i<4;i++) {
        int r = r0 + mf*16 + 4*hi + i;
        int n = r & 7, l = r >> 3;
        float v[4]; float ss = 0.f;
#pragma unroll
        for (int nf=0;nf<4;nf++){ v[nf] = acc[mf][nf][i] + bi[nf]; ss += v[nf]*v[nf]; }
        float sc = 1.0f;
        if (dnorm) {
          ss += __shfl_xor(ss, 1);
          ss += __shfl_xor(ss, 2);
          ss += __shfl_xor(ss, 4);
          ss += __shfl_xor(ss, 8);
          sc = qsc / fmaxf(sqrtf(ss), 1e-12f);
        }
        size_t base = (((size_t)n*12 + hh)*1024 + l)*64;
#pragma unroll
        for (int nf=0;nf<4;nf++)
          dst[base + nf*16 + lo] = f2h(v[nf]*sc);
      }
  } else {
#pragma unroll
    for (int nf=0; nf<4; nf++) {
      int j = j0 + nf*16 + lo;
      float bi = bias[j];
#pragma unroll
      for (int mf=0; mf<4; mf++)
#pragma unroll
        for (int i=0;i<4;i++) {
          int r = r0 + mf*16 + 4*hi + i;
          outp[(size_t)r*768 + j] = acc[mf][nf][i] + bi;
        }
    }
  }
}

// ---------------- V transpose: (N,H,L,D) -> (N,H,D,L) ----------------
__global__ __launch_bounds__(256) void transpose_kernel(const u16* __restrict__ vh, u16* __restrict__ vt){
  __shared__ u16 tile[64*72];   // [l(64)][d] padded stride 72
  const int nh = blockIdx.y, lt = blockIdx.x, tid = threadIdx.x;
  const int r = tid >> 2, c0 = (tid & 3) * 16;
  const u16* src = vh + (size_t)nh*65536 + (size_t)(lt*64 + r)*64 + c0;
  u32x4 a = *(const u32x4*)src, b = *(const u32x4*)(src + 8);
  *(u32x4*)(tile + r*72 + c0)     = a;
  *(u32x4*)(tile + r*72 + c0 + 8) = b;
  __syncthreads();
  u16x8 o0, o1;
#pragma unroll
  for (int s=0;s<8;s++){ o0[s] = tile[(c0+s)*72 + r]; o1[s] = tile[(c0+8+s)*72 + r]; }
  u16* dst = vt + (size_t)nh*65536 + (size_t)r*1024 + lt*64 + c0;
  *(u16x8*)dst       = o0;
  *(u16x8*)(dst + 8) = o1;
}

// ---------------- flash attention (cosine-bounded: no running max needed) ----------------
// grid (16 q-tiles, 96 n*h) -> 1536 blocks = 6/CU; LDS 16KB single-buffer + VGPR<=85
// (__launch_bounds__ 256,6) -> 24 waves/CU, 2x the old TLP. Each wave owns 16 q rows.
// Tiles are XOR-swizzled [64][64] (128B rows):
//   K[k][d]: 16B-slot s of row k holds d-slot s ^ (k&7); read k0/k1 at (hi)^(lo&7),
//   (hi+4)^(lo&7) -> distinct banks per 8-lane phase (gemm-verified 0 conflicts).
//   VT[d][k]: k-chunks (8B) PERMUTED q8 = (hi<<2 | kf) ^ ((d&7)<<1) so each lane's
//   4 PV fragments come from 2 b128 reads (was 16 conflicting b64 reads).
// Raw s_barrier + lgkmcnt(0) (no vmcnt drain) keeps the next-tile global prefetch
// in flight across the barrier (T4).
// Swapped QK^T in log2 domain; p = exp2(s) fits fp16 (no max/rescale);
// row sums via all-ones MFMA16; P feeds PV directly from registers.
__global__ __launch_bounds__(256, 6) void flash_kernel(
    const u16* __restrict__ qh, const u16* __restrict__ kh, const u16* __restrict__ vt,
    u16* __restrict__ obuf, const float* __restrict__ hsv, const float* __restrict__ lsp)
{
  __shared__ u16 lK[64*64];    // [k][d] swizzled 16B slots
  __shared__ u16 lVT[64*64];   // [d][k] permuted+swizzled 8B chunks
  // XCD-locality remap: 12 heads x 16 q-tiles per XCD (3MB K+V resident in L2)
  const int lin = blockIdx.y*16 + blockIdx.x;
  const int xcd = lin & 7, g = lin >> 3;
  const int nh = xcd + 8*(g >> 4);
  const int qt = g & 15;
  const int h = nh % 12, n = nh / 12;
  const u16* Qp = qh + (size_t)nh*65536;
  const u16* Kp = kh + (size_t)nh*65536;
  const u16* Vp = vt + (size_t)nh*65536;
  const int tid = threadIdx.x, lane = tid & 63, w = tid >> 6;
  const int lo = lane & 15, hi = lane >> 4;
  const int e = lo & 7;

  // Q fragments: lane holds Q[q=lo][d = hi*8 + j] (+32)
  h8 qa0, qa1;
  {
    const u16* qrow = Qp + (size_t)(qt*64 + w*16 + lo)*64 + hi*8;
    qa0 = *(const h8*)qrow;
    qa1 = *(const h8*)(qrow + 32);
  }
  const f32x4 zero = {0.f,0.f,0.f,0.f};
  f32x4 oA[4] = {zero,zero,zero,zero};   // O^T[d=db*16+4hi+i][q=lo]
  f32x4 lA4 = zero;                      // row sums via ones-MFMA
  const h4 ones = {(f16)1.f,(f16)1.f,(f16)1.f,(f16)1.f};

  // fp16-overflow guard (0 for these inputs; uniform branch if ever nonzero)
  float OFF;
  {
    float b = __expf(fminf(lsp[h], 4.6051701859880913680f)) * 1.4426950408889634f;
    OFF = fmaxf(b - 15.5f, 0.f);
  }

  const int sr = tid >> 2;          // stage row (k for lK, d for lVT), 0..63
  const int c4 = tid & 3;           // stage 16B-column group
  const int sx1 = sr & 7;           // K slot16 XOR
  const int sx2 = (sr & 7) << 1;    // VT chunk8 XOR (even)

  u32x4 ka, kb, va, vb;
  ka = *(const u32x4*)(Kp + (size_t)sr*64 + c4*16);
  kb = *(const u32x4*)(Kp + (size_t)sr*64 + c4*16 + 8);
  va = *(const u32x4*)(Vp + (size_t)sr*1024 + c4*16);
  vb = *(const u32x4*)(Vp + (size_t)sr*1024 + c4*16 + 8);

  for (int t = 0; t < 16; ++t) {
    // ---- stage regs -> LDS (swizzled) ----
    {
      u16* kr = lK + sr*64;
      *(u32x4*)(kr + (((2*c4)   ^ sx1) << 3)) = ka;
      *(u32x4*)(kr + (((2*c4+1) ^ sx1) << 3)) = kb;
      u16* vr = lVT + sr*64;
      *(u32x2*)(vr + (((( 0|c4) ^ sx2) << 2))) = (u32x2){va[0], va[1]};
      *(u32x2*)(vr + (((( 4|c4) ^ sx2) << 2))) = (u32x2){va[2], va[3]};
      *(u32x2*)(vr + (((( 8|c4) ^ sx2) << 2))) = (u32x2){vb[0], vb[1]};
      *(u32x2*)(vr + ((((12|c4) ^ sx2) << 2))) = (u32x2){vb[2], vb[3]};
    }
    asm volatile("s_waitcnt lgkmcnt(0)" ::: "memory");
    __builtin_amdgcn_sched_barrier(0);
    __builtin_amdgcn_s_barrier();                // tile visible to all waves
    if (t < 15) {  // prefetch next tile into regs; stays in flight across barrier
      ka = *(const u32x4*)(Kp + (size_t)(t+1)*4096 + (size_t)sr*64 + c4*16);
      kb = *(const u32x4*)(Kp + (size_t)(t+1)*4096 + (size_t)sr*64 + c4*16 + 8);
      va = *(const u32x4*)(Vp + (size_t)sr*1024 + (t+1)*64 + c4*16);
      vb = *(const u32x4*)(Vp + (size_t)sr*1024 + (t+1)*64 + c4*16 + 8);
    }
    // ---- S^T = K . Q^T ----
    f32x4 sa[4];
#pragma unroll
    for (int kf=0; kf<4; kf++) {
      const u16* krow = lK + (kf*16 + lo)*64;
      h8 k0 = *(const h8*)(krow + (((hi  ) ^ e) << 3));
      h8 k1 = *(const h8*)(krow + (((hi+4) ^ e) << 3));
      sa[kf] = MFMA32(k1, qa1, MFMA32(k0, qa0, zero));
    }
    if (OFF != 0.f) {
#pragma unroll
      for (int kf=0;kf<4;kf++)
#pragma unroll
        for (int i=0;i<4;i++) sa[kf][i] -= OFF;
    }
    // ---- p = exp2(s), packed into mfma16 B-operand layout ----
    h4 pa[4];
#pragma unroll
    for (int kf=0;kf<4;kf++) {
      h2 a01 = pkrtz(fast_exp2(sa[kf][0]), fast_exp2(sa[kf][1]));
      h2 a23 = pkrtz(fast_exp2(sa[kf][2]), fast_exp2(sa[kf][3]));
      pa[kf] = __builtin_shufflevector(a01, a23, 0, 1, 2, 3);
    }
    // ---- row sums on the matrix pipe ----
#pragma unroll
    for (int kf=0;kf<4;kf++) lA4 = MFMA16(ones, pa[kf], lA4);
    // ---- PV: O^T += VT-frag x P-frag (2 b128 V-reads per db) ----
#pragma unroll
    for (int db=0; db<4; db++) {
      const u16* vrow = lVT + (db*16 + lo)*64;
      h8 v01 = *(const h8*)(vrow + ((((2*hi  ) ^ e) << 3)));
      h8 v23 = *(const h8*)(vrow + ((((2*hi+1) ^ e) << 3)));
      oA[db] = MFMA16(__builtin_shufflevector(v01, v01, 0,1,2,3), pa[0], oA[db]);
      oA[db] = MFMA16(__builtin_shufflevector(v01, v01, 4,5,6,7), pa[1], oA[db]);
      oA[db] = MFMA16(__builtin_shufflevector(v23, v23, 0,1,2,3), pa[2], oA[db]);
      oA[db] = MFMA16(__builtin_shufflevector(v23, v23, 4,5,6,7), pa[3], oA[db]);
    }
    asm volatile("s_waitcnt lgkmcnt(0)" ::: "memory"); // my reads retired
    __builtin_amdgcn_sched_barrier(0);
    __builtin_amdgcn_s_barrier();                      // safe to restage
  }
  // epilogue: O[q][d] = O^T / l * head_scale, store fp16 into (L,N,C)
  float inv = hsv[h] / lA4[0];
  int l = qt*64 + w*16 + lo;
  u16* dst = obuf + ((size_t)l*8 + n)*768 + h*64;
#pragma unroll
  for (int db=0; db<4; db++) {
    u16x4 pk;
#pragma unroll
    for (int i=0;i<4;i++) pk[i] = f2h(oA[db][i] * inv);
    *(u16x4*)(dst + db*16 + hi*4) = pk;
  }
}

extern "C" void kernel_launch(void* const* d_in, const int* in_sizes, int n_in,
                              void* d_out, int out_size, void* d_ws, size_t ws_size,
                              hipStream_t stream)
{
  (void)in_sizes; (void)n_in; (void)out_size; (void)ws_size;
  const float* x  = (const float*)d_in[0];
  const float* w1 = (const float*)d_in[1];
  const float* b1 = (const float*)d_in[2];
  const float* ls = (const float*)d_in[3];
  const float* hs = (const float*)d_in[4];
  const float* w2 = (const float*)d_in[5];
  const float* b2 = (const float*)d_in[6];
  float* out = (float*)d_out;

  u16* x_bf  = (u16*)d_ws;            // 8192 x 768  (reused as ob after GEMM1)
  u16* w1_bf = x_bf  + 6291456;       // 2304 x 768
  u16* w2_bf = w1_bf + 1769472;       // 768 x 768
  u16* qh    = w2_bf + 589824;        // (N,H,L,D) normalized (+ls*log2e on q)
  u16* kh    = qh    + 6291456;
  u16* vh    = kh    + 6291456;
  u16* vt    = vh    + 6291456;       // (N,H,D,L)
  u16* ob    = x_bf;                  // (L,N,C) fp16, aliases x_bf

  cvt3_kernel<<<8448, 256, 0, stream>>>(x, x_bf, w1, w1_bf, w2, w2_bf);
  gemm_kernel<<<dim3(64,18), 256, 0, stream>>>(x_bf, w1_bf, b1, 0, qh, kh, vh, nullptr, ls);
  transpose_kernel<<<dim3(16,96), 256, 0, stream>>>(vh, vt);
  flash_kernel<<<dim3(16,96), 256, 0, stream>>>(qh, kh, vt, ob, hs, ls);
  gemm_kernel<<<dim3(64,6), 256, 0, stream>>>(ob, w2_bf, b2, 1, nullptr, nullptr, nullptr, out, ls);
}